// Round 1
// baseline (965.908 us; speedup 1.0000x reference)
//
#include <hip/hip_runtime.h>
#include <math.h>

// B=1, L=256, DP=128, DB=128, H=8, DH=32, H*DH=256
// Workspace layout (floats):
//   PN  [65536][128]           @ 0          (33.5 MB)  LN(pair), original frame
//   Qt  [i][h][n][d] 256x8x256x32 @ 8388608 (67 MB)
//   Kt  [j][h][n][d]           @ 25165824   (67 MB)
//   Vt  [k][h][j][d]           @ 41943040   (67 MB)
//   Lg  [h][i][j] 8x256x256    @ 58720256   (2.1 MB)   logits -> attn in place
//   O   [i][k][e] 65536x256    @ 8388608    (reuses Qt, dead after k_logits)
// Total ws: 236,978,176 bytes.

#define PN_OFF 0
#define QT_OFF 8388608
#define KT_OFF 25165824
#define VT_OFF 41943040
#define LG_OFF 58720256

// ---------------- K1: LayerNorm(pair) -> PN ----------------
__global__ __launch_bounds__(256) void k_ln(const float* __restrict__ x,
                                            const float* __restrict__ g,
                                            const float* __restrict__ b,
                                            float* __restrict__ y) {
  int p = blockIdx.x * 4 + (threadIdx.x >> 6);
  int lane = threadIdx.x & 63;
  const float* row = x + (size_t)p * 128;
  float x0 = row[lane], x1 = row[lane + 64];
  float s = x0 + x1, ss = x0 * x0 + x1 * x1;
#pragma unroll
  for (int off = 32; off; off >>= 1) {
    s += __shfl_xor(s, off);
    ss += __shfl_xor(ss, off);
  }
  float m = s * (1.0f / 128.0f);
  float v = ss * (1.0f / 128.0f) - m * m;
  float inv = rsqrtf(v + 1e-5f);
  float* o = y + (size_t)p * 128;
  o[lane] = (x0 - m) * inv * g[lane] + b[lane];
  o[lane + 64] = (x1 - m) * inv * g[lane + 64] + b[lane + 64];
}

// ---------------- K2: LayerNorm(bias) -> bproj into Lg ----------------
// position p=(r,sc) contributes Lg[h][i=sc][j=r] = dot(BN[r,sc,:], Wb[:,h])
__global__ __launch_bounds__(256) void k_lnbias_bproj(const float* __restrict__ x,
                                                      const float* __restrict__ g,
                                                      const float* __restrict__ b,
                                                      const float* __restrict__ Wb,
                                                      float* __restrict__ Lg) {
  int p = blockIdx.x * 4 + (threadIdx.x >> 6);
  int lane = threadIdx.x & 63;
  int r = p >> 8, sc = p & 255;
  const float* row = x + (size_t)p * 128;
  float x0 = row[lane], x1 = row[lane + 64];
  float s = x0 + x1, ss = x0 * x0 + x1 * x1;
#pragma unroll
  for (int off = 32; off; off >>= 1) {
    s += __shfl_xor(s, off);
    ss += __shfl_xor(ss, off);
  }
  float m = s * (1.0f / 128.0f);
  float v = ss * (1.0f / 128.0f) - m * m;
  float inv = rsqrtf(v + 1e-5f);
  float y0 = (x0 - m) * inv * g[lane] + b[lane];
  float y1 = (x1 - m) * inv * g[lane + 64] + b[lane + 64];
#pragma unroll
  for (int h = 0; h < 8; ++h) {
    float part = y0 * Wb[lane * 8 + h] + y1 * Wb[(lane + 64) * 8 + h];
#pragma unroll
    for (int off = 32; off; off >>= 1) part += __shfl_xor(part, off);
    if (lane == 0) Lg[(size_t)h * 65536 + sc * 256 + r] = part;
  }
}

// ---------------- K3: projections PN @ {Wq,Wk,Wv} -> Qt,Kt,Vt ----------------
// block: 16 positions (fixed r, 16 consecutive s), 256 threads = one output col each
__global__ __launch_bounds__(256) void k_proj(const float* __restrict__ PN,
                                              const float* __restrict__ Wq,
                                              const float* __restrict__ Wk,
                                              const float* __restrict__ Wv,
                                              float* __restrict__ Qt,
                                              float* __restrict__ Kt,
                                              float* __restrict__ Vt) {
  __shared__ float pl[16 * 128];
  const int t = threadIdx.x;
  const int r = blockIdx.x >> 4;
  const int s0 = (blockIdx.x & 15) << 4;
  {
    const float4* src = (const float4*)(PN + ((size_t)(r * 256 + s0)) * 128);
    float4* dst = (float4*)pl;
    dst[t] = src[t];
    dst[t + 256] = src[t + 256];
  }
  __syncthreads();
  const int h = t >> 5, d = t & 31;
  float acc[16];

  // Q (scaled by 1/sqrt(DH))
#pragma unroll
  for (int p = 0; p < 16; ++p) acc[p] = 0.f;
  for (int c = 0; c < 128; ++c) {
    float w = Wq[c * 256 + t];
#pragma unroll
    for (int p = 0; p < 16; ++p) acc[p] += pl[p * 128 + c] * w;
  }
#pragma unroll
  for (int p = 0; p < 16; ++p)
    Qt[(((size_t)(r * 8 + h)) * 256 + (s0 + p)) * 32 + d] = acc[p] * 0.17677669529663687f;

  // K (scaled by 1/sqrt(L) = 1/16)
#pragma unroll
  for (int p = 0; p < 16; ++p) acc[p] = 0.f;
  for (int c = 0; c < 128; ++c) {
    float w = Wk[c * 256 + t];
#pragma unroll
    for (int p = 0; p < 16; ++p) acc[p] += pl[p * 128 + c] * w;
  }
#pragma unroll
  for (int p = 0; p < 16; ++p)
    Kt[(((size_t)(r * 8 + h)) * 256 + (s0 + p)) * 32 + d] = acc[p] * 0.0625f;

  // V  (note transposed placement: Vt[k=s][h][j=r][d])
#pragma unroll
  for (int p = 0; p < 16; ++p) acc[p] = 0.f;
  for (int c = 0; c < 128; ++c) {
    float w = Wv[c * 256 + t];
#pragma unroll
    for (int p = 0; p < 16; ++p) acc[p] += pl[p * 128 + c] * w;
  }
#pragma unroll
  for (int p = 0; p < 16; ++p)
    Vt[(((size_t)((s0 + p) * 8 + h)) * 256 + r) * 32 + d] = acc[p];
}

// ---------------- K4: logits Lg[h,i,j] += sum_{n,d} Qt[i,h,n,d]*Kt[j,h,n,d] ----
// grid: (16 = 4 i-tiles x 4 j-tiles, 8 heads, 4 k-slabs of 2048). 64x64 tile,
// 256 threads as 16x16, 4x4 outputs/thread. atomicAdd onto bproj-initialized Lg.
__global__ __launch_bounds__(256) void k_logits(const float* __restrict__ Qt,
                                                const float* __restrict__ Kt,
                                                float* __restrict__ Lg) {
  __shared__ float qs[64 * 65];
  __shared__ float ks[64 * 65];
  const int t = threadIdx.x;
  const int it = blockIdx.x >> 2, jt = blockIdx.x & 3;
  const int h = blockIdx.y;
  const int kslab = blockIdx.z;
  const int tx = t & 15, ty = t >> 4;
  float acc[4][4] = {};
  for (int ch = 0; ch < 32; ++ch) {
    __syncthreads();
    const int cbase = kslab * 2048 + ch * 64;
#pragma unroll
    for (int u = 0; u < 4; ++u) {
      int idx = t + u * 256;  // 0..1023
      int row = idx >> 4, c4 = (idx & 15) << 2;
      float4 q4 = *(const float4*)(Qt + (((size_t)((it * 64 + row) * 8 + h)) << 13) + cbase + c4);
      qs[row * 65 + c4 + 0] = q4.x;
      qs[row * 65 + c4 + 1] = q4.y;
      qs[row * 65 + c4 + 2] = q4.z;
      qs[row * 65 + c4 + 3] = q4.w;
      float4 k4 = *(const float4*)(Kt + (((size_t)((jt * 64 + row) * 8 + h)) << 13) + cbase + c4);
      ks[row * 65 + c4 + 0] = k4.x;
      ks[row * 65 + c4 + 1] = k4.y;
      ks[row * 65 + c4 + 2] = k4.z;
      ks[row * 65 + c4 + 3] = k4.w;
    }
    __syncthreads();
    for (int cc = 0; cc < 64; ++cc) {
      float qv[4], kv[4];
#pragma unroll
      for (int rr = 0; rr < 4; ++rr) qv[rr] = qs[(ty * 4 + rr) * 65 + cc];
#pragma unroll
      for (int c2 = 0; c2 < 4; ++c2) kv[c2] = ks[(tx * 4 + c2) * 65 + cc];
#pragma unroll
      for (int rr = 0; rr < 4; ++rr)
#pragma unroll
        for (int c2 = 0; c2 < 4; ++c2) acc[rr][c2] += qv[rr] * kv[c2];
    }
  }
#pragma unroll
  for (int rr = 0; rr < 4; ++rr)
#pragma unroll
    for (int c2 = 0; c2 < 4; ++c2)
      atomicAdd(&Lg[(size_t)h * 65536 + (size_t)(it * 64 + ty * 4 + rr) * 256 +
                    (jt * 64 + tx * 4 + c2)],
                acc[rr][c2]);
}

// ---------------- K5: masked softmax over j, in place on Lg ----------------
__global__ __launch_bounds__(256) void k_softmax(float* __restrict__ Lg,
                                                 const int* __restrict__ mask) {
  const int i = blockIdx.x, h = blockIdx.y;
  const int j = threadIdx.x;
  __shared__ float red[4], red2[4];
  float* row = Lg + (size_t)h * 65536 + (size_t)i * 256;
  bool mi = (mask[i] == 0);
  float x = row[j];
  if (mi || (mask[j] == 0)) x = -1e9f;
  float mx = x;
#pragma unroll
  for (int off = 32; off; off >>= 1) mx = fmaxf(mx, __shfl_xor(mx, off));
  int wave = j >> 6;
  if ((j & 63) == 0) red[wave] = mx;
  __syncthreads();
  mx = fmaxf(fmaxf(red[0], red[1]), fmaxf(red[2], red[3]));
  float e = expf(x - mx);
  float sm = e;
#pragma unroll
  for (int off = 32; off; off >>= 1) sm += __shfl_xor(sm, off);
  if ((j & 63) == 0) red2[wave] = sm;
  __syncthreads();
  sm = red2[0] + red2[1] + red2[2] + red2[3];
  row[j] = e / sm;
}

// ---------------- K6: O[i,k,e] = sum_j attn[h,i,j] * Vt[k,h,j,d] ----------------
// Per h: GEMM [256 i x 256 j] @ [256 j x 8192 (k,d)]. grid (32 kd-tiles, 4 i-tiles, 8 h)
// 256 threads as 8(ty:i) x 32(tx:d), 8x8 outputs/thread (cols strided by 32 for banks).
__global__ __launch_bounds__(256) void k_av(const float* __restrict__ Lg,
                                            const float* __restrict__ Vt,
                                            float* __restrict__ O) {
  __shared__ float As[64 * 33];
  __shared__ float Bs[32 * 257];
  const int t = threadIdx.x;
  const int nt = blockIdx.x;  // kd tile: n0 = nt*256
  const int it = blockIdx.y;
  const int h = blockIdx.z;
  const int tx = t & 31, ty = t >> 5;
  float acc[8][8] = {};
  for (int ch = 0; ch < 8; ++ch) {  // j chunks of 32
    __syncthreads();
#pragma unroll
    for (int u = 0; u < 2; ++u) {
      int idx = t + u * 256;
      int il = idx >> 3, j4 = (idx & 7) << 2;
      float4 a4 = *(const float4*)(Lg + (size_t)h * 65536 + (size_t)(it * 64 + il) * 256 +
                                   ch * 32 + j4);
      As[il * 33 + j4 + 0] = a4.x;
      As[il * 33 + j4 + 1] = a4.y;
      As[il * 33 + j4 + 2] = a4.z;
      As[il * 33 + j4 + 3] = a4.w;
    }
#pragma unroll
    for (int u = 0; u < 8; ++u) {
      int idx = t + u * 256;
      int jl = idx >> 6, n4 = idx & 63;
      int nl = n4 << 2;              // n_loc
      int kk = nt * 8 + (nl >> 5), d = nl & 31;
      float4 b4 = *(const float4*)(Vt + (((size_t)(kk * 8 + h)) * 256 + (ch * 32 + jl)) * 32 + d);
      Bs[jl * 257 + nl + 0] = b4.x;
      Bs[jl * 257 + nl + 1] = b4.y;
      Bs[jl * 257 + nl + 2] = b4.z;
      Bs[jl * 257 + nl + 3] = b4.w;
    }
    __syncthreads();
    for (int j = 0; j < 32; ++j) {
      float av[8], bv[8];
#pragma unroll
      for (int rr = 0; rr < 8; ++rr) av[rr] = As[(ty * 8 + rr) * 33 + j];
#pragma unroll
      for (int cc = 0; cc < 8; ++cc) bv[cc] = Bs[j * 257 + tx + cc * 32];
#pragma unroll
      for (int rr = 0; rr < 8; ++rr)
#pragma unroll
        for (int cc = 0; cc < 8; ++cc) acc[rr][cc] += av[rr] * bv[cc];
    }
  }
#pragma unroll
  for (int rr = 0; rr < 8; ++rr)
#pragma unroll
    for (int cc = 0; cc < 8; ++cc)
      O[(size_t)(it * 64 + ty * 8 + rr) * 65536 + (size_t)(nt * 8 + cc) * 256 + h * 32 + tx] =
          acc[rr][cc];
}

// ---------------- K7: gate + output proj + transpose + mask ----------------
// block: fixed k, 8 consecutive i. res[i,k,c] = sum_e sigm(PN[k,i]@Wg+bg)*O[i,k,e]*Wo[e,c]+bo
// write to out[(k*256+i)*128+c], zero if masked.
__global__ __launch_bounds__(256) void k_final(const float* __restrict__ PN,
                                               const float* __restrict__ O,
                                               const float* __restrict__ Wg,
                                               const float* __restrict__ bg,
                                               const float* __restrict__ Wo,
                                               const float* __restrict__ bo,
                                               const int* __restrict__ mask,
                                               float* __restrict__ out) {
  __shared__ float pl[8 * 128];
  __shared__ float Ot[8 * 256];
  __shared__ float GO[8 * 256];
  const int t = threadIdx.x;
  const int kk = blockIdx.x >> 5;
  const int i0 = (blockIdx.x & 31) << 3;
  {
    const float4* src = (const float4*)(PN + ((size_t)kk * 256 + i0) * 128);
    ((float4*)pl)[t] = src[t];
  }
#pragma unroll
  for (int u = 0; u < 2; ++u) {
    int idx = t + u * 256;
    int p = idx >> 6, e4 = (idx & 63) << 2;
    *(float4*)&Ot[p * 256 + e4] =
        *(const float4*)(O + (size_t)(i0 + p) * 65536 + (size_t)kk * 256 + e4);
  }
  __syncthreads();
  {
    float accg[8];
#pragma unroll
    for (int p = 0; p < 8; ++p) accg[p] = bg[t];
    for (int c = 0; c < 128; ++c) {
      float w = Wg[c * 256 + t];
#pragma unroll
      for (int p = 0; p < 8; ++p) accg[p] += pl[p * 128 + c] * w;
    }
#pragma unroll
    for (int p = 0; p < 8; ++p)
      GO[p * 256 + t] = Ot[p * 256 + t] / (1.f + expf(-accg[p]));
  }
  __syncthreads();
  {
    const int c = t & 127, pg = t >> 7;  // p = pg*4+q
    float acc[4];
#pragma unroll
    for (int q = 0; q < 4; ++q) acc[q] = bo[c];
    for (int e = 0; e < 256; ++e) {
      float w = Wo[e * 128 + c];
#pragma unroll
      for (int q = 0; q < 4; ++q) acc[q] += GO[(pg * 4 + q) * 256 + e] * w;
    }
    bool mk = (mask[kk] == 0);
#pragma unroll
    for (int q = 0; q < 4; ++q) {
      int i = i0 + pg * 4 + q;
      bool z = mk || (mask[i] == 0);
      out[((size_t)kk * 256 + i) * 128 + c] = z ? 0.f : acc[q];
    }
  }
}

extern "C" void kernel_launch(void* const* d_in, const int* in_sizes, int n_in,
                              void* d_out, int out_size, void* d_ws, size_t ws_size,
                              hipStream_t stream) {
  const float* pair = (const float*)d_in[0];
  const float* bias = (const float*)d_in[1];
  const int* mask = (const int*)d_in[2];
  const float* g_pair = (const float*)d_in[3];
  const float* b_pair = (const float*)d_in[4];
  const float* g_bias = (const float*)d_in[5];
  const float* b_bias = (const float*)d_in[6];
  const float* Wq = (const float*)d_in[7];
  const float* Wk = (const float*)d_in[8];
  const float* Wv = (const float*)d_in[9];
  const float* Wb = (const float*)d_in[10];
  const float* Wg = (const float*)d_in[11];
  const float* bg = (const float*)d_in[12];
  const float* Wo = (const float*)d_in[13];
  const float* bo = (const float*)d_in[14];
  float* out = (float*)d_out;
  float* ws = (float*)d_ws;
  float* PN = ws + PN_OFF;
  float* Qt = ws + QT_OFF;
  float* Kt = ws + KT_OFF;
  float* Vt = ws + VT_OFF;
  float* Lg = ws + LG_OFF;
  float* O = Qt;  // Qt dead after k_logits

  k_ln<<<16384, 256, 0, stream>>>(pair, g_pair, b_pair, PN);
  k_lnbias_bproj<<<16384, 256, 0, stream>>>(bias, g_bias, b_bias, Wb, Lg);
  k_proj<<<4096, 256, 0, stream>>>(PN, Wq, Wk, Wv, Qt, Kt, Vt);
  k_logits<<<dim3(16, 8, 4), 256, 0, stream>>>(Qt, Kt, Lg);
  k_softmax<<<dim3(256, 8), 256, 0, stream>>>(Lg, mask);
  k_av<<<dim3(32, 4, 8), 256, 0, stream>>>(Lg, Vt, O);
  k_final<<<8192, 256, 0, stream>>>(PN, O, Wg, bg, Wo, bo, mask, out);
}

// Round 2
// 513.768 us; speedup vs baseline: 1.8800x; 1.8800x over previous
//
#include <hip/hip_runtime.h>
#include <math.h>

// B=1, L=256, DP=128, DB=128, H=8, DH=32, H*DH=256
// All heavy GEMMs in bf16 MFMA (16x16x32), fp32 accumulate.
//
// Fragment layout facts (HW-verified per guide):
//   A-frag: lane holds A[m=lane&15][k=(lane>>4)*8 + j], j=0..7  (8 bf16 = 16B)
//   B-frag: lane holds B[k=(lane>>4)*8 + j][n=lane&15]
//   D:      lane holds D[row=(lane>>4)*4+reg][col=lane&15], reg=0..3 (fp32)
//
// Workspace (byte offsets):
//   PNb  u16 [65536][128]      @ 0            16,777,216   LN(pair) bf16
//   Qtb  u16 [8][256][8192]    @ 16777216     33,554,432   [h][i][n*32+d]
//   Ktb  u16 [8][256][8192]    @ 50331648     33,554,432   [h][j][n*32+d]
//   Vtb  u16 [8][8192][256]    @ 83886080     33,554,432   [h][k*32+d][j]
//   Gb   u16 [65536][256]      @ 117440512    33,554,432   gate, row=i*256+k
//   GOb  u16 [65536][256]      @ 150994944    33,554,432   gated O, row=i*256+k
//   Lg   f32 [8][256][256]     @ 184549376     2,097,152   bproj+logits
//   Ab   u16 [8][256][256]     @ 186646528     1,048,576   attn bf16
//   Wtb  u16 [4][256][128]     @ 187695104       262,144   WqWkWvWg transposed [n][k]
//   Wotb u16 [128][256]        @ 187957248        65,536   Wo transposed [c][e]
// total 188,022,784 B

typedef unsigned short u16;
typedef __attribute__((ext_vector_type(8))) short short8;
typedef __attribute__((ext_vector_type(4))) float float4v;

__device__ __forceinline__ u16 f2bf(float f) {
  unsigned int u = __float_as_uint(f);
  u += 0x7FFFu + ((u >> 16) & 1u);
  return (u16)(u >> 16);
}
__device__ __forceinline__ float bf2f(u16 h) {
  return __uint_as_float(((unsigned int)h) << 16);
}

// ---------------- K1: LayerNorm(pair) -> PNb (bf16) ----------------
__global__ __launch_bounds__(256) void k_ln(const float* __restrict__ x,
                                            const float* __restrict__ g,
                                            const float* __restrict__ b,
                                            u16* __restrict__ y) {
  int p = blockIdx.x * 4 + (threadIdx.x >> 6);
  int lane = threadIdx.x & 63;
  float2 xv = *(const float2*)(x + (size_t)p * 128 + lane * 2);
  float x0 = xv.x, x1 = xv.y;
  float s = x0 + x1, ss = x0 * x0 + x1 * x1;
#pragma unroll
  for (int off = 32; off; off >>= 1) {
    s += __shfl_xor(s, off);
    ss += __shfl_xor(ss, off);
  }
  float m = s * (1.0f / 128.0f);
  float v = ss * (1.0f / 128.0f) - m * m;
  float inv = rsqrtf(v + 1e-5f);
  float2 gv = *(const float2*)(g + lane * 2);
  float2 bv = *(const float2*)(b + lane * 2);
  float y0 = (x0 - m) * inv * gv.x + bv.x;
  float y1 = (x1 - m) * inv * gv.y + bv.y;
  unsigned int pk = (unsigned int)f2bf(y0) | ((unsigned int)f2bf(y1) << 16);
  *(unsigned int*)(y + (size_t)p * 128 + lane * 2) = pk;
}

// ---------------- K2: LayerNorm(bias) -> bproj into Lg (fp32) ----------------
__global__ __launch_bounds__(256) void k_lnbias_bproj(const float* __restrict__ x,
                                                      const float* __restrict__ g,
                                                      const float* __restrict__ b,
                                                      const float* __restrict__ Wb,
                                                      float* __restrict__ Lg) {
  int p = blockIdx.x * 4 + (threadIdx.x >> 6);
  int lane = threadIdx.x & 63;
  int r = p >> 8, sc = p & 255;
  const float* row = x + (size_t)p * 128;
  float x0 = row[lane], x1 = row[lane + 64];
  float s = x0 + x1, ss = x0 * x0 + x1 * x1;
#pragma unroll
  for (int off = 32; off; off >>= 1) {
    s += __shfl_xor(s, off);
    ss += __shfl_xor(ss, off);
  }
  float m = s * (1.0f / 128.0f);
  float v = ss * (1.0f / 128.0f) - m * m;
  float inv = rsqrtf(v + 1e-5f);
  float y0 = (x0 - m) * inv * g[lane] + b[lane];
  float y1 = (x1 - m) * inv * g[lane + 64] + b[lane + 64];
#pragma unroll
  for (int h = 0; h < 8; ++h) {
    float part = y0 * Wb[lane * 8 + h] + y1 * Wb[(lane + 64) * 8 + h];
#pragma unroll
    for (int off = 32; off; off >>= 1) part += __shfl_xor(part, off);
    if (lane == 0) Lg[(size_t)h * 65536 + sc * 256 + r] = part;
  }
}

// ---------------- K3: weight convert/transpose to bf16 ----------------
__global__ __launch_bounds__(256) void k_wcvt(const float* __restrict__ Wq,
                                              const float* __restrict__ Wk,
                                              const float* __restrict__ Wv,
                                              const float* __restrict__ Wg,
                                              const float* __restrict__ Wo,
                                              u16* __restrict__ Wtb,
                                              u16* __restrict__ Wotb) {
  int idx = blockIdx.x * 256 + threadIdx.x;
  if (idx < 131072) {
    int w = idx >> 15, r = idx & 32767;
    int n = r >> 7, k = r & 127;  // out [n][k]
    const float* W = (w == 0) ? Wq : (w == 1) ? Wk : (w == 2) ? Wv : Wg;
    Wtb[(size_t)w * 32768 + n * 128 + k] = f2bf(W[k * 256 + n]);
  } else {
    int r = idx - 131072;  // Wo [256 e][128 c] -> Wotb[c][e]
    int c = r >> 8, e = r & 255;
    Wotb[c * 256 + e] = f2bf(Wo[e * 128 + c]);
  }
}

// ---------------- K4: fused Q/K/V/gate projections (MFMA) ----------------
// grid 512 blocks x 256 thr; block = 128 PN rows, wave = 32 rows.
__global__ __launch_bounds__(256) void k_proj_mfma(const u16* __restrict__ PNb,
                                                   const u16* __restrict__ Wtb,
                                                   const float* __restrict__ bg,
                                                   u16* __restrict__ Qtb,
                                                   u16* __restrict__ Ktb,
                                                   u16* __restrict__ Vtb,
                                                   u16* __restrict__ Gb) {
  const int wid = threadIdx.x >> 6, lane = threadIdx.x & 63;
  const int mrow = lane & 15, quad = lane >> 4;
  const int m0 = blockIdx.x * 128 + wid * 32;
  short8 afr[2][4];
#pragma unroll
  for (int mt = 0; mt < 2; ++mt) {
    const u16* ar = PNb + (size_t)(m0 + mt * 16 + mrow) * 128 + quad * 8;
#pragma unroll
    for (int kk = 0; kk < 4; ++kk) afr[mt][kk] = *(const short8*)(ar + kk * 32);
  }
  for (int w = 0; w < 4; ++w) {
    const u16* Wt = Wtb + (size_t)w * 32768;
    for (int nt = 0; nt < 16; ++nt) {
      float4v acc[2];
#pragma unroll
      for (int mt = 0; mt < 2; ++mt) acc[mt] = (float4v){0.f, 0.f, 0.f, 0.f};
      const u16* br = Wt + (size_t)(nt * 16 + mrow) * 128 + quad * 8;
#pragma unroll
      for (int kk = 0; kk < 4; ++kk) {
        short8 bfr = *(const short8*)(br + kk * 32);
#pragma unroll
        for (int mt = 0; mt < 2; ++mt)
          acc[mt] = __builtin_amdgcn_mfma_f32_16x16x32_bf16(afr[mt][kk], bfr, acc[mt], 0, 0, 0);
      }
      const int n = nt * 16 + mrow;  // D col = lane&15
      const int h = n >> 5, d = n & 31;
      float bgn = (w == 3) ? bg[n] : 0.f;
#pragma unroll
      for (int mt = 0; mt < 2; ++mt) {
#pragma unroll
        for (int reg = 0; reg < 4; ++reg) {
          int p = m0 + mt * 16 + quad * 4 + reg;  // PN row = r*256+s
          int r = p >> 8, sc = p & 255;
          float v = acc[mt][reg];
          if (w == 0) {
            Qtb[(size_t)h * 2097152 + (size_t)r * 8192 + sc * 32 + d] =
                f2bf(v * 0.17677669529663687f);
          } else if (w == 1) {
            Ktb[(size_t)h * 2097152 + (size_t)r * 8192 + sc * 32 + d] = f2bf(v * 0.0625f);
          } else if (w == 2) {
            Vtb[(size_t)h * 2097152 + (size_t)(sc * 32 + d) * 256 + r] = f2bf(v);
          } else {
            float gv = 1.f / (1.f + expf(-(v + bgn)));
            Gb[(size_t)(sc * 256 + r) * 256 + n] = f2bf(gv);
          }
        }
      }
    }
  }
}

// ---------------- K5: logits (MFMA) Lg[h,i,j] += Q.K over 8192 ----------------
// grid (4 tiles of 128x128, 8 h, 8 kslabs of 1024); atomicAdd epilogue.
__global__ __launch_bounds__(256) void k_logits_mfma(const u16* __restrict__ Qtb,
                                                     const u16* __restrict__ Ktb,
                                                     float* __restrict__ Lg) {
  __shared__ u16 Qs[128 * 40];
  __shared__ u16 Ks[128 * 40];
  const int t = threadIdx.x;
  const int wid = t >> 6, lane = t & 63;
  const int mrow = lane & 15, quad = lane >> 4;
  const int i0 = (blockIdx.x >> 1) * 128, j0 = (blockIdx.x & 1) * 128;
  const int h = blockIdx.y;
  const int wi = wid >> 1, wj = wid & 1;  // wave tile 64x64
  float4v acc[4][4];
#pragma unroll
  for (int a = 0; a < 4; ++a)
#pragma unroll
    for (int bq = 0; bq < 4; ++bq) acc[a][bq] = (float4v){0.f, 0.f, 0.f, 0.f};

  const u16* qg = Qtb + (size_t)h * 2097152 + (size_t)i0 * 8192;
  const u16* kg = Ktb + (size_t)h * 2097152 + (size_t)j0 * 8192;
  for (int ck = 0; ck < 32; ++ck) {
    const int kbase = blockIdx.z * 1024 + ck * 32;
    __syncthreads();
#pragma unroll
    for (int u = 0; u < 2; ++u) {
      int id = u * 256 + t;
      int r = id >> 2, c8 = (id & 3) * 8;
      *(short8*)&Qs[r * 40 + c8] = *(const short8*)(qg + (size_t)r * 8192 + kbase + c8);
      *(short8*)&Ks[r * 40 + c8] = *(const short8*)(kg + (size_t)r * 8192 + kbase + c8);
    }
    __syncthreads();
    short8 afr[4], bfr[4];
#pragma unroll
    for (int mt = 0; mt < 4; ++mt)
      afr[mt] = *(const short8*)&Qs[(wi * 64 + mt * 16 + mrow) * 40 + quad * 8];
#pragma unroll
    for (int nn = 0; nn < 4; ++nn)
      bfr[nn] = *(const short8*)&Ks[(wj * 64 + nn * 16 + mrow) * 40 + quad * 8];
#pragma unroll
    for (int mt = 0; mt < 4; ++mt)
#pragma unroll
      for (int nn = 0; nn < 4; ++nn)
        acc[mt][nn] = __builtin_amdgcn_mfma_f32_16x16x32_bf16(afr[mt], bfr[nn], acc[mt][nn], 0, 0, 0);
  }
#pragma unroll
  for (int mt = 0; mt < 4; ++mt)
#pragma unroll
    for (int nn = 0; nn < 4; ++nn) {
      int j = j0 + wj * 64 + nn * 16 + mrow;
#pragma unroll
      for (int reg = 0; reg < 4; ++reg) {
        int i = i0 + wi * 64 + mt * 16 + quad * 4 + reg;
        atomicAdd(&Lg[(size_t)h * 65536 + (size_t)i * 256 + j], acc[mt][nn][reg]);
      }
    }
}

// ---------------- K6: masked softmax over j -> Ab (bf16) ----------------
__global__ __launch_bounds__(256) void k_softmax(const float* __restrict__ Lg,
                                                 const int* __restrict__ mask,
                                                 u16* __restrict__ Ab) {
  const int i = blockIdx.x, h = blockIdx.y;
  const int j = threadIdx.x;
  __shared__ float red[4], red2[4];
  const float* row = Lg + (size_t)h * 65536 + (size_t)i * 256;
  bool mi = (mask[i] == 0);
  float x = row[j];
  if (mi || (mask[j] == 0)) x = -1e9f;
  float mx = x;
#pragma unroll
  for (int off = 32; off; off >>= 1) mx = fmaxf(mx, __shfl_xor(mx, off));
  int wave = j >> 6;
  if ((j & 63) == 0) red[wave] = mx;
  __syncthreads();
  mx = fmaxf(fmaxf(red[0], red[1]), fmaxf(red[2], red[3]));
  float e = expf(x - mx);
  float sm = e;
#pragma unroll
  for (int off = 32; off; off >>= 1) sm += __shfl_xor(sm, off);
  if ((j & 63) == 0) red2[wave] = sm;
  __syncthreads();
  sm = red2[0] + red2[1] + red2[2] + red2[3];
  Ab[(size_t)h * 65536 + (size_t)i * 256 + j] = f2bf(e / sm);
}

// ---------------- K7: AV (MFMA) + gate -> GOb (bf16) ----------------
// grid (8 n-slabs of 1024 kd, 4 i-tiles of 64, 8 h). wave = 64i x 256kd.
__global__ __launch_bounds__(256) void k_av_mfma(const u16* __restrict__ Ab,
                                                 const u16* __restrict__ Vtb,
                                                 const u16* __restrict__ Gb,
                                                 u16* __restrict__ GOb) {
  __shared__ u16 As[64 * 264];
  const int t = threadIdx.x;
  const int wid = t >> 6, lane = t & 63;
  const int mrow = lane & 15, quad = lane >> 4;
  const int h = blockIdx.z;
  const int i0 = blockIdx.y * 64;
  const u16* ag = Ab + (size_t)h * 65536 + (size_t)i0 * 256;
#pragma unroll
  for (int u = 0; u < 8; ++u) {
    int id = u * 256 + t;
    int r = id >> 5, c8 = (id & 31) * 8;
    *(short8*)&As[r * 264 + c8] = *(const short8*)(ag + (size_t)r * 256 + c8);
  }
  __syncthreads();
  const u16* vg = Vtb + (size_t)h * 2097152;
  for (int nt4 = 0; nt4 < 4; ++nt4) {
    const int nbase = blockIdx.x * 1024 + wid * 256 + nt4 * 64;
    float4v acc[4][4];
#pragma unroll
    for (int a = 0; a < 4; ++a)
#pragma unroll
      for (int bq = 0; bq < 4; ++bq) acc[a][bq] = (float4v){0.f, 0.f, 0.f, 0.f};
#pragma unroll
    for (int kk = 0; kk < 8; ++kk) {
      short8 afr[4], bfr[4];
#pragma unroll
      for (int mt = 0; mt < 4; ++mt)
        afr[mt] = *(const short8*)&As[(mt * 16 + mrow) * 264 + kk * 32 + quad * 8];
#pragma unroll
      for (int nn = 0; nn < 4; ++nn)
        bfr[nn] = *(const short8*)(vg + (size_t)(nbase + nn * 16 + mrow) * 256 + kk * 32 + quad * 8);
#pragma unroll
      for (int mt = 0; mt < 4; ++mt)
#pragma unroll
        for (int nn = 0; nn < 4; ++nn)
          acc[mt][nn] = __builtin_amdgcn_mfma_f32_16x16x32_bf16(afr[mt], bfr[nn], acc[mt][nn], 0, 0, 0);
    }
#pragma unroll
    for (int mt = 0; mt < 4; ++mt)
#pragma unroll
      for (int nn = 0; nn < 4; ++nn) {
        int n = nbase + nn * 16 + mrow;
        int kslot = n >> 5, d = n & 31;
        int e = h * 32 + d;
#pragma unroll
        for (int reg = 0; reg < 4; ++reg) {
          int i = i0 + mt * 16 + quad * 4 + reg;
          size_t idx = ((size_t)i * 256 + kslot) * 256 + e;
          float gv = bf2f(Gb[idx]);
          GOb[idx] = f2bf(acc[mt][nn][reg] * gv);
        }
      }
  }
}

// ---------------- K8: output proj (MFMA) + bias + transpose + mask ----------------
// grid 512 blocks; block = 128 GO rows, wave = 32 rows. N=128, K=256.
__global__ __launch_bounds__(256) void k_out_mfma(const u16* __restrict__ GOb,
                                                  const u16* __restrict__ Wotb,
                                                  const float* __restrict__ bo,
                                                  const int* __restrict__ mask,
                                                  float* __restrict__ out) {
  const int wid = threadIdx.x >> 6, lane = threadIdx.x & 63;
  const int mrow = lane & 15, quad = lane >> 4;
  const int m0 = blockIdx.x * 128 + wid * 32;
  short8 afr[2][8];
#pragma unroll
  for (int mt = 0; mt < 2; ++mt) {
    const u16* ar = GOb + (size_t)(m0 + mt * 16 + mrow) * 256 + quad * 8;
#pragma unroll
    for (int kk = 0; kk < 8; ++kk) afr[mt][kk] = *(const short8*)(ar + kk * 32);
  }
  for (int nt = 0; nt < 8; ++nt) {
    float4v acc[2];
#pragma unroll
    for (int mt = 0; mt < 2; ++mt) acc[mt] = (float4v){0.f, 0.f, 0.f, 0.f};
    const u16* br = Wotb + (size_t)(nt * 16 + mrow) * 256 + quad * 8;
#pragma unroll
    for (int kk = 0; kk < 8; ++kk) {
      short8 bfr = *(const short8*)(br + kk * 32);
#pragma unroll
      for (int mt = 0; mt < 2; ++mt)
        acc[mt] = __builtin_amdgcn_mfma_f32_16x16x32_bf16(afr[mt][kk], bfr, acc[mt], 0, 0, 0);
    }
    const int c = nt * 16 + mrow;
    float bov = bo[c];
#pragma unroll
    for (int mt = 0; mt < 2; ++mt) {
#pragma unroll
      for (int reg = 0; reg < 4; ++reg) {
        int m = m0 + mt * 16 + quad * 4 + reg;  // = i*256 + k
        int i = m >> 8, kq = m & 255;
        float v = acc[mt][reg] + bov;
        bool z = (mask[i] == 0) || (mask[kq] == 0);
        out[((size_t)kq * 256 + i) * 128 + c] = z ? 0.f : v;
      }
    }
  }
}

extern "C" void kernel_launch(void* const* d_in, const int* in_sizes, int n_in,
                              void* d_out, int out_size, void* d_ws, size_t ws_size,
                              hipStream_t stream) {
  const float* pair = (const float*)d_in[0];
  const float* bias = (const float*)d_in[1];
  const int* mask = (const int*)d_in[2];
  const float* g_pair = (const float*)d_in[3];
  const float* b_pair = (const float*)d_in[4];
  const float* g_bias = (const float*)d_in[5];
  const float* b_bias = (const float*)d_in[6];
  const float* Wq = (const float*)d_in[7];
  const float* Wk = (const float*)d_in[8];
  const float* Wv = (const float*)d_in[9];
  const float* Wb = (const float*)d_in[10];
  const float* Wg = (const float*)d_in[11];
  const float* bg = (const float*)d_in[12];
  const float* Wo = (const float*)d_in[13];
  const float* bo = (const float*)d_in[14];
  float* out = (float*)d_out;
  char* ws = (char*)d_ws;

  u16* PNb = (u16*)(ws + 0);
  u16* Qtb = (u16*)(ws + 16777216);
  u16* Ktb = (u16*)(ws + 50331648);
  u16* Vtb = (u16*)(ws + 83886080);
  u16* Gb = (u16*)(ws + 117440512);
  u16* GOb = (u16*)(ws + 150994944);
  float* Lg = (float*)(ws + 184549376);
  u16* Ab = (u16*)(ws + 186646528);
  u16* Wtb = (u16*)(ws + 187695104);
  u16* Wotb = (u16*)(ws + 187957248);

  k_ln<<<16384, 256, 0, stream>>>(pair, g_pair, b_pair, PNb);
  k_wcvt<<<640, 256, 0, stream>>>(Wq, Wk, Wv, Wg, Wo, Wtb, Wotb);
  k_lnbias_bproj<<<16384, 256, 0, stream>>>(bias, g_bias, b_bias, Wb, Lg);
  k_proj_mfma<<<512, 256, 0, stream>>>(PNb, Wtb, bg, Qtb, Ktb, Vtb, Gb);
  k_logits_mfma<<<dim3(4, 8, 8), 256, 0, stream>>>(Qtb, Ktb, Lg);
  k_softmax<<<dim3(256, 8), 256, 0, stream>>>(Lg, mask, Ab);
  k_av_mfma<<<dim3(8, 4, 8), 256, 0, stream>>>(Ab, Vtb, Gb, GOb);
  k_out_mfma<<<512, 256, 0, stream>>>(GOb, Wotb, bo, mask, out);
}

// Round 5
// 454.125 us; speedup vs baseline: 2.1270x; 1.1313x over previous
//
#include <hip/hip_runtime.h>
#include <math.h>

// B=1, L=256, DP=128, DB=128, H=8, DH=32, H*DH=256
// bf16 MFMA 16x16x32; all global stores wide/contiguous via LDS transpose
// epilogues. NO atomics / cross-kernel RMW: every ws cell is written by
// exactly one kernel (plain stores) before any reader -> bit-deterministic.
//
// Fragment layouts (HW-verified):
//   A-frag: lane holds A[m=lane&15][k=(lane>>4)*8+j], j=0..7 (16B)
//   B-frag: lane holds B[k=(lane>>4)*8+j][n=lane&15]
//   D:      lane holds D[row=(lane>>4)*4+reg][col=lane&15]
//
// Workspace (byte offsets):
//   PNb  u16 [65536][128]    @ 0            16,777,216   LN(pair), row p=r*256+sc
//   Qr   u16 [65536][256]    @ 16777216     33,554,432   [p=(i*256+sc)][(h,d)]
//   Kr   u16 [65536][256]    @ 50331648     33,554,432   [p=(j*256+sc)][(h,d)]
//   Vtb  u16 [8][8192][256]  @ 83886080     33,554,432   [h][k*32+d][j]
//   Gb   u16 [65536][256]    @ 117440512    33,554,432   row = i*256+k
//   GOb  u16 [65536][256]    @ 150994944    33,554,432
//   Bp   f32 [8][256][256]   @ 184549376     2,097,152   bias projection
//   Ab   u16 [8][256][256]   @ 186646528     1,048,576   attn bf16
//   Wtb  u16 [4][256][128]   @ 187695104       262,144   W{q,k,v,g}^T [n][k]
//   Wotb u16 [128][256]      @ 187957248        65,536   Wo^T [c][e]
//   Lg2  f32 [8][8][256][256]@ 188022784    16,777,216   split-K logit slices
// total 204,800,000 B

typedef unsigned short u16;
typedef __attribute__((ext_vector_type(8))) short short8;
typedef __attribute__((ext_vector_type(4))) float float4v;

__device__ __forceinline__ u16 f2bf(float f) {
  unsigned int u = __float_as_uint(f);
  u += 0x7FFFu + ((u >> 16) & 1u);
  return (u16)(u >> 16);
}
__device__ __forceinline__ float bf2f(u16 h) {
  return __uint_as_float(((unsigned int)h) << 16);
}

// ---------------- K1: LayerNorm(pair) -> PNb (bf16) ----------------
__global__ __launch_bounds__(256) void k_ln(const float* __restrict__ x,
                                            const float* __restrict__ g,
                                            const float* __restrict__ b,
                                            u16* __restrict__ y) {
  int p = blockIdx.x * 4 + (threadIdx.x >> 6);
  int lane = threadIdx.x & 63;
  float2 xv = *(const float2*)(x + (size_t)p * 128 + lane * 2);
  float x0 = xv.x, x1 = xv.y;
  float s = x0 + x1, ss = x0 * x0 + x1 * x1;
#pragma unroll
  for (int off = 32; off; off >>= 1) {
    s += __shfl_xor(s, off);
    ss += __shfl_xor(ss, off);
  }
  float m = s * (1.0f / 128.0f);
  float v = ss * (1.0f / 128.0f) - m * m;
  float inv = rsqrtf(v + 1e-5f);
  float2 gv = *(const float2*)(g + lane * 2);
  float2 bv = *(const float2*)(b + lane * 2);
  float y0 = (x0 - m) * inv * gv.x + bv.x;
  float y1 = (x1 - m) * inv * gv.y + bv.y;
  unsigned int pk = (unsigned int)f2bf(y0) | ((unsigned int)f2bf(y1) << 16);
  *(unsigned int*)(y + (size_t)p * 128 + lane * 2) = pk;
}

// ---------------- K2: LayerNorm(bias) -> Bp (fp32, own buffer) ----------------
__global__ __launch_bounds__(256) void k_lnbias_bproj(const float* __restrict__ x,
                                                      const float* __restrict__ g,
                                                      const float* __restrict__ b,
                                                      const float* __restrict__ Wb,
                                                      float* __restrict__ Bp) {
  int p = blockIdx.x * 4 + (threadIdx.x >> 6);
  int lane = threadIdx.x & 63;
  int r = p >> 8, sc = p & 255;
  const float* row = x + (size_t)p * 128;
  float x0 = row[lane], x1 = row[lane + 64];
  float s = x0 + x1, ss = x0 * x0 + x1 * x1;
#pragma unroll
  for (int off = 32; off; off >>= 1) {
    s += __shfl_xor(s, off);
    ss += __shfl_xor(ss, off);
  }
  float m = s * (1.0f / 128.0f);
  float v = ss * (1.0f / 128.0f) - m * m;
  float inv = rsqrtf(v + 1e-5f);
  float y0 = (x0 - m) * inv * g[lane] + b[lane];
  float y1 = (x1 - m) * inv * g[lane + 64] + b[lane + 64];
#pragma unroll
  for (int h = 0; h < 8; ++h) {
    float part = y0 * Wb[lane * 8 + h] + y1 * Wb[(lane + 64) * 8 + h];
#pragma unroll
    for (int off = 32; off; off >>= 1) part += __shfl_xor(part, off);
    if (lane == 0) Bp[(size_t)h * 65536 + sc * 256 + r] = part;
  }
}

// ---------------- K3: weight convert/transpose to bf16 ----------------
__global__ __launch_bounds__(256) void k_wcvt(const float* __restrict__ Wq,
                                              const float* __restrict__ Wk,
                                              const float* __restrict__ Wv,
                                              const float* __restrict__ Wg,
                                              const float* __restrict__ Wo,
                                              u16* __restrict__ Wtb,
                                              u16* __restrict__ Wotb) {
  int idx = blockIdx.x * 256 + threadIdx.x;
  if (idx < 131072) {
    int w = idx >> 15, r = idx & 32767;
    int n = r >> 7, k = r & 127;  // out [n][k]
    const float* W = (w == 0) ? Wq : (w == 1) ? Wk : (w == 2) ? Wv : Wg;
    Wtb[(size_t)w * 32768 + n * 128 + k] = f2bf(W[k * 256 + n]);
  } else {
    int r = idx - 131072;  // Wo [256 e][128 c] -> Wotb[c][e]
    int c = r >> 8, e = r & 255;
    Wotb[c * 256 + e] = f2bf(Wo[e * 128 + c]);
  }
}

// ---------------- K4: Q/K/gate projections (MFMA, LDS-transpose epilogue) ----
// block = 128 consecutive PN rows (fixed r, sc in [s0,s0+128)). wave = 32 rows.
__global__ __launch_bounds__(256) void k_proj_qkg(const u16* __restrict__ PNb,
                                                  const u16* __restrict__ Wtb,
                                                  const float* __restrict__ bg,
                                                  u16* __restrict__ Qr,
                                                  u16* __restrict__ Kr,
                                                  u16* __restrict__ Gb) {
  __shared__ u16 sb[128 * 136];
  const int t = threadIdx.x;
  const int wid = t >> 6, lane = t & 63;
  const int mrow = lane & 15, quad = lane >> 4;
  const int p0 = blockIdx.x * 128;
  const int r = p0 >> 8, s0 = p0 & 255;
  short8 afr[2][4];
#pragma unroll
  for (int mt = 0; mt < 2; ++mt) {
    const u16* ar = PNb + (size_t)(p0 + wid * 32 + mt * 16 + mrow) * 128 + quad * 8;
#pragma unroll
    for (int kk = 0; kk < 4; ++kk) afr[mt][kk] = *(const short8*)(ar + kk * 32);
  }
#pragma unroll
  for (int wi = 0; wi < 3; ++wi) {
    const int wsel = (wi == 0) ? 0 : (wi == 1) ? 1 : 3;
    const u16* Wt = Wtb + (size_t)wsel * 32768;
    for (int half = 0; half < 2; ++half) {
#pragma unroll
      for (int nt8 = 0; nt8 < 8; ++nt8) {
        const int nt = half * 8 + nt8;
        float4v acc[2];
        acc[0] = (float4v){0.f, 0.f, 0.f, 0.f};
        acc[1] = (float4v){0.f, 0.f, 0.f, 0.f};
        const u16* br = Wt + (size_t)(nt * 16 + mrow) * 128 + quad * 8;
#pragma unroll
        for (int kk = 0; kk < 4; ++kk) {
          short8 bfr = *(const short8*)(br + kk * 32);
#pragma unroll
          for (int mt = 0; mt < 2; ++mt)
            acc[mt] = __builtin_amdgcn_mfma_f32_16x16x32_bf16(afr[mt][kk], bfr, acc[mt], 0, 0, 0);
        }
        const int n = nt * 16 + mrow;
        const float bgn = (wi == 2) ? bg[n] : 0.f;
#pragma unroll
        for (int mt = 0; mt < 2; ++mt) {
#pragma unroll
          for (int reg = 0; reg < 4; ++reg) {
            float v = acc[mt][reg];
            if (wi == 0) v *= 0.17677669529663687f;
            else if (wi == 1) v *= 0.0625f;
            else v = 1.f / (1.f + expf(-(v + bgn)));
            sb[(wid * 32 + mt * 16 + quad * 4 + reg) * 136 + nt8 * 16 + mrow] = f2bf(v);
          }
        }
      }
      __syncthreads();
      // 128 rows x 16 col-groups-of-8 = 2048 units; 256 thr x 8 iters.
      if (wi < 2) {
        u16* dst = (wi == 0) ? Qr : Kr;
#pragma unroll
        for (int it = 0; it < 8; ++it) {
          int u = it * 256 + t;
          int row = u >> 4, c8 = (u & 15) * 8;
          short8 vv = *(const short8*)&sb[row * 136 + c8];
          *(short8*)(dst + (size_t)(p0 + row) * 256 + half * 128 + c8) = vv;
        }
      } else {
#pragma unroll
        for (int it = 0; it < 8; ++it) {
          int u = it * 256 + t;
          int row = u >> 4, c8 = (u & 15) * 8;
          short8 vv = *(const short8*)&sb[row * 136 + c8];
          *(short8*)(Gb + ((size_t)(s0 + row) * 256 + r) * 256 + half * 128 + c8) = vv;
        }
      }
      __syncthreads();
    }
  }
}

// ---------------- K5: V projection (MFMA), tiled by fixed sc, 128 r-rows ----
__global__ __launch_bounds__(256) void k_projv(const u16* __restrict__ PNb,
                                               const u16* __restrict__ Wtb,
                                               u16* __restrict__ Vtb) {
  __shared__ u16 sb[128 * 136];
  const int t = threadIdx.x;
  const int wid = t >> 6, lane = t & 63;
  const int mrow = lane & 15, quad = lane >> 4;
  const int sc = blockIdx.x >> 1;
  const int r0 = (blockIdx.x & 1) * 128;
  short8 afr[2][4];
#pragma unroll
  for (int mt = 0; mt < 2; ++mt) {
    const int p = (r0 + wid * 32 + mt * 16 + mrow) * 256 + sc;
    const u16* ar = PNb + (size_t)p * 128 + quad * 8;
#pragma unroll
    for (int kk = 0; kk < 4; ++kk) afr[mt][kk] = *(const short8*)(ar + kk * 32);
  }
  const u16* Wt = Wtb + (size_t)2 * 32768;
  for (int half = 0; half < 2; ++half) {
#pragma unroll
    for (int nt8 = 0; nt8 < 8; ++nt8) {
      const int nt = half * 8 + nt8;
      float4v acc[2];
      acc[0] = (float4v){0.f, 0.f, 0.f, 0.f};
      acc[1] = (float4v){0.f, 0.f, 0.f, 0.f};
      const u16* br = Wt + (size_t)(nt * 16 + mrow) * 128 + quad * 8;
#pragma unroll
      for (int kk = 0; kk < 4; ++kk) {
        short8 bfr = *(const short8*)(br + kk * 32);
#pragma unroll
        for (int mt = 0; mt < 2; ++mt)
          acc[mt] = __builtin_amdgcn_mfma_f32_16x16x32_bf16(afr[mt][kk], bfr, acc[mt], 0, 0, 0);
      }
#pragma unroll
      for (int mt = 0; mt < 2; ++mt)
#pragma unroll
        for (int reg = 0; reg < 4; ++reg)
          sb[(wid * 32 + mt * 16 + quad * 4 + reg) * 136 + nt8 * 16 + mrow] =
              f2bf(acc[mt][reg]);
    }
    __syncthreads();
#pragma unroll
    for (int it = 0; it < 8; ++it) {
      int u = it * 256 + t;
      int c = u & 127, rg = u >> 7;
      short8 vv;
#pragma unroll
      for (int q = 0; q < 8; ++q) vv[q] = (short)sb[(rg * 8 + q) * 136 + c];
      int n = half * 128 + c;
      int h = n >> 5, d = n & 31;
      *(short8*)(Vtb + (size_t)h * 2097152 + (size_t)(sc * 32 + d) * 256 + r0 + rg * 8) = vv;
    }
    __syncthreads();
  }
}

// ---------------- K6: logits (MFMA), split-K plain stores to Lg2 ----------------
// grid (4 = 2 i-tiles x 2 j-tiles, 8 h, 8 kslabs). Lg2[z][h][i][j] partial sums.
__global__ __launch_bounds__(256) void k_logits_mfma(const u16* __restrict__ Qr,
                                                     const u16* __restrict__ Kr,
                                                     float* __restrict__ Lg2) {
  __shared__ u16 Qs[128 * 40];
  __shared__ u16 Ks[128 * 40];
  const int t = threadIdx.x;
  const int wid = t >> 6, lane = t & 63;
  const int mrow = lane & 15, quad = lane >> 4;
  const int i0 = (blockIdx.x >> 1) * 128, j0 = (blockIdx.x & 1) * 128;
  const int h = blockIdx.y;
  const int wi = wid >> 1, wj = wid & 1;
  float4v acc[4][4];
#pragma unroll
  for (int a = 0; a < 4; ++a)
#pragma unroll
    for (int bq = 0; bq < 4; ++bq) acc[a][bq] = (float4v){0.f, 0.f, 0.f, 0.f};

  for (int ck = 0; ck < 32; ++ck) {
    const int sc = blockIdx.z * 32 + ck;
    __syncthreads();
#pragma unroll
    for (int u = 0; u < 2; ++u) {
      int id = u * 256 + t;
      int rr = id >> 2, c8 = (id & 3) * 8;
      *(short8*)&Qs[rr * 40 + c8] =
          *(const short8*)(Qr + ((size_t)((i0 + rr) * 256 + sc)) * 256 + h * 32 + c8);
      *(short8*)&Ks[rr * 40 + c8] =
          *(const short8*)(Kr + ((size_t)((j0 + rr) * 256 + sc)) * 256 + h * 32 + c8);
    }
    __syncthreads();
    short8 afr[4], bfr[4];
#pragma unroll
    for (int mt = 0; mt < 4; ++mt)
      afr[mt] = *(const short8*)&Qs[(wi * 64 + mt * 16 + mrow) * 40 + quad * 8];
#pragma unroll
    for (int nn = 0; nn < 4; ++nn)
      bfr[nn] = *(const short8*)&Ks[(wj * 64 + nn * 16 + mrow) * 40 + quad * 8];
#pragma unroll
    for (int mt = 0; mt < 4; ++mt)
#pragma unroll
      for (int nn = 0; nn < 4; ++nn)
        acc[mt][nn] = __builtin_amdgcn_mfma_f32_16x16x32_bf16(afr[mt], bfr[nn], acc[mt][nn], 0, 0, 0);
  }
  float* slab = Lg2 + ((size_t)blockIdx.z * 8 + h) * 65536;
#pragma unroll
  for (int mt = 0; mt < 4; ++mt)
#pragma unroll
    for (int nn = 0; nn < 4; ++nn) {
      int j = j0 + wj * 64 + nn * 16 + mrow;
#pragma unroll
      for (int reg = 0; reg < 4; ++reg) {
        int i = i0 + wi * 64 + mt * 16 + quad * 4 + reg;
        slab[(size_t)i * 256 + j] = acc[mt][nn][reg];
      }
    }
}

// ---------------- K7: masked softmax over j (sum Bp + 8 slabs) -> Ab ----------
__global__ __launch_bounds__(256) void k_softmax(const float* __restrict__ Bp,
                                                 const float* __restrict__ Lg2,
                                                 const int* __restrict__ mask,
                                                 u16* __restrict__ Ab) {
  const int i = blockIdx.x, h = blockIdx.y;
  const int j = threadIdx.x;
  __shared__ float red[4], red2[4];
  const size_t off = (size_t)h * 65536 + (size_t)i * 256 + j;
  float x = Bp[off];
#pragma unroll
  for (int z = 0; z < 8; ++z) x += Lg2[(size_t)z * 524288 + off];
  bool mi = (mask[i] == 0);
  if (mi || (mask[j] == 0)) x = -1e9f;
  float mx = x;
#pragma unroll
  for (int off2 = 32; off2; off2 >>= 1) mx = fmaxf(mx, __shfl_xor(mx, off2));
  int wave = j >> 6;
  if ((j & 63) == 0) red[wave] = mx;
  __syncthreads();
  mx = fmaxf(fmaxf(red[0], red[1]), fmaxf(red[2], red[3]));
  float e = expf(x - mx);
  float sm = e;
#pragma unroll
  for (int off2 = 32; off2; off2 >>= 1) sm += __shfl_xor(sm, off2);
  if ((j & 63) == 0) red2[wave] = sm;
  __syncthreads();
  sm = red2[0] + red2[1] + red2[2] + red2[3];
  Ab[off] = f2bf(e / sm);
}

// ---------------- K8: AV (MFMA) + gate -> GOb (bf16) ----------------
__global__ __launch_bounds__(256) void k_av_mfma(const u16* __restrict__ Ab,
                                                 const u16* __restrict__ Vtb,
                                                 const u16* __restrict__ Gb,
                                                 u16* __restrict__ GOb) {
  __shared__ u16 As[64 * 264];
  const int t = threadIdx.x;
  const int wid = t >> 6, lane = t & 63;
  const int mrow = lane & 15, quad = lane >> 4;
  const int h = blockIdx.z;
  const int i0 = blockIdx.y * 64;
  const u16* ag = Ab + (size_t)h * 65536 + (size_t)i0 * 256;
#pragma unroll
  for (int u = 0; u < 8; ++u) {
    int id = u * 256 + t;
    int rr = id >> 5, c8 = (id & 31) * 8;
    *(short8*)&As[rr * 264 + c8] = *(const short8*)(ag + (size_t)rr * 256 + c8);
  }
  __syncthreads();
  const u16* vg = Vtb + (size_t)h * 2097152;
  for (int nt4 = 0; nt4 < 4; ++nt4) {
    const int nbase = blockIdx.x * 1024 + wid * 256 + nt4 * 64;
    float4v acc[4][4];
#pragma unroll
    for (int a = 0; a < 4; ++a)
#pragma unroll
      for (int bq = 0; bq < 4; ++bq) acc[a][bq] = (float4v){0.f, 0.f, 0.f, 0.f};
#pragma unroll
    for (int kk = 0; kk < 8; ++kk) {
      short8 afr[4], bfr[4];
#pragma unroll
      for (int mt = 0; mt < 4; ++mt)
        afr[mt] = *(const short8*)&As[(mt * 16 + mrow) * 264 + kk * 32 + quad * 8];
#pragma unroll
      for (int nn = 0; nn < 4; ++nn)
        bfr[nn] = *(const short8*)(vg + (size_t)(nbase + nn * 16 + mrow) * 256 + kk * 32 + quad * 8);
#pragma unroll
      for (int mt = 0; mt < 4; ++mt)
#pragma unroll
        for (int nn = 0; nn < 4; ++nn)
          acc[mt][nn] = __builtin_amdgcn_mfma_f32_16x16x32_bf16(afr[mt], bfr[nn], acc[mt][nn], 0, 0, 0);
    }
#pragma unroll
    for (int mt = 0; mt < 4; ++mt)
#pragma unroll
      for (int nn = 0; nn < 4; ++nn) {
        int n = nbase + nn * 16 + mrow;
        int kslot = n >> 5, d = n & 31;
        int e = h * 32 + d;
#pragma unroll
        for (int reg = 0; reg < 4; ++reg) {
          int i = i0 + mt * 16 + quad * 4 + reg;
          size_t idx = ((size_t)i * 256 + kslot) * 256 + e;
          float gv = bf2f(Gb[idx]);
          GOb[idx] = f2bf(acc[mt][nn][reg] * gv);
        }
      }
  }
}

// ---------------- K9: output proj (MFMA) + bias + transpose + mask ----------------
__global__ __launch_bounds__(256) void k_out_mfma(const u16* __restrict__ GOb,
                                                  const u16* __restrict__ Wotb,
                                                  const float* __restrict__ bo,
                                                  const int* __restrict__ mask,
                                                  float* __restrict__ out) {
  const int wid = threadIdx.x >> 6, lane = threadIdx.x & 63;
  const int mrow = lane & 15, quad = lane >> 4;
  const int m0 = blockIdx.x * 128 + wid * 32;
  short8 afr[2][8];
#pragma unroll
  for (int mt = 0; mt < 2; ++mt) {
    const u16* ar = GOb + (size_t)(m0 + mt * 16 + mrow) * 256 + quad * 8;
#pragma unroll
    for (int kk = 0; kk < 8; ++kk) afr[mt][kk] = *(const short8*)(ar + kk * 32);
  }
  for (int nt = 0; nt < 8; ++nt) {
    float4v acc[2];
    acc[0] = (float4v){0.f, 0.f, 0.f, 0.f};
    acc[1] = (float4v){0.f, 0.f, 0.f, 0.f};
    const u16* br = Wotb + (size_t)(nt * 16 + mrow) * 256 + quad * 8;
#pragma unroll
    for (int kk = 0; kk < 8; ++kk) {
      short8 bfr = *(const short8*)(br + kk * 32);
#pragma unroll
      for (int mt = 0; mt < 2; ++mt)
        acc[mt] = __builtin_amdgcn_mfma_f32_16x16x32_bf16(afr[mt][kk], bfr, acc[mt], 0, 0, 0);
    }
    const int c = nt * 16 + mrow;
    float bov = bo[c];
#pragma unroll
    for (int mt = 0; mt < 2; ++mt) {
#pragma unroll
      for (int reg = 0; reg < 4; ++reg) {
        int m = m0 + mt * 16 + quad * 4 + reg;  // = i*256 + k
        int i = m >> 8, kq = m & 255;
        float v = acc[mt][reg] + bov;
        bool z = (mask[i] == 0) || (mask[kq] == 0);
        out[((size_t)kq * 256 + i) * 128 + c] = z ? 0.f : v;
      }
    }
  }
}

extern "C" void kernel_launch(void* const* d_in, const int* in_sizes, int n_in,
                              void* d_out, int out_size, void* d_ws, size_t ws_size,
                              hipStream_t stream) {
  const float* pair = (const float*)d_in[0];
  const float* bias = (const float*)d_in[1];
  const int* mask = (const int*)d_in[2];
  const float* g_pair = (const float*)d_in[3];
  const float* b_pair = (const float*)d_in[4];
  const float* g_bias = (const float*)d_in[5];
  const float* b_bias = (const float*)d_in[6];
  const float* Wq = (const float*)d_in[7];
  const float* Wk = (const float*)d_in[8];
  const float* Wv = (const float*)d_in[9];
  const float* Wb = (const float*)d_in[10];
  const float* Wg = (const float*)d_in[11];
  const float* bg = (const float*)d_in[12];
  const float* Wo = (const float*)d_in[13];
  const float* bo = (const float*)d_in[14];
  float* out = (float*)d_out;
  char* ws = (char*)d_ws;

  u16* PNb = (u16*)(ws + 0);
  u16* Qr = (u16*)(ws + 16777216);
  u16* Kr = (u16*)(ws + 50331648);
  u16* Vtb = (u16*)(ws + 83886080);
  u16* Gb = (u16*)(ws + 117440512);
  u16* GOb = (u16*)(ws + 150994944);
  float* Bp = (float*)(ws + 184549376);
  u16* Ab = (u16*)(ws + 186646528);
  u16* Wtb = (u16*)(ws + 187695104);
  u16* Wotb = (u16*)(ws + 187957248);
  float* Lg2 = (float*)(ws + 188022784);

  k_ln<<<16384, 256, 0, stream>>>(pair, g_pair, b_pair, PNb);
  k_wcvt<<<640, 256, 0, stream>>>(Wq, Wk, Wv, Wg, Wo, Wtb, Wotb);
  k_lnbias_bproj<<<16384, 256, 0, stream>>>(bias, g_bias, b_bias, Wb, Bp);
  k_proj_qkg<<<512, 256, 0, stream>>>(PNb, Wtb, bg, Qr, Kr, Gb);
  k_projv<<<512, 256, 0, stream>>>(PNb, Wtb, Vtb);
  k_logits_mfma<<<dim3(4, 8, 8), 256, 0, stream>>>(Qr, Kr, Lg2);
  k_softmax<<<dim3(256, 8), 256, 0, stream>>>(Bp, Lg2, mask, Ab);
  k_av_mfma<<<dim3(8, 4, 8), 256, 0, stream>>>(Ab, Vtb, Gb, GOb);
  k_out_mfma<<<512, 256, 0, stream>>>(GOb, Wotb, bo, mask, out);
}

// Round 6
// 372.375 us; speedup vs baseline: 2.5939x; 1.2195x over previous
//
#include <hip/hip_runtime.h>
#include <math.h>

// B=1, L=256, DP=128, DB=128, H=8, DH=32, H*DH=256
// bf16 MFMA 16x16x32; all global stores wide/contiguous via LDS transpose
// epilogues. NO atomics / cross-kernel RMW: every ws cell is written by
// exactly one kernel (plain stores) before any reader -> bit-deterministic.
//
// Fragment layouts (HW-verified):
//   A-frag: lane holds A[m=lane&15][k=(lane>>4)*8+j], j=0..7 (16B)
//   B-frag: lane holds B[k=(lane>>4)*8+j][n=lane&15]
//   D:      lane holds D[row=(lane>>4)*4+reg][col=lane&15]
//
// Workspace (byte offsets):
//   PNb  u16 [65536][128]    @ 0            16,777,216   LN(pair), row p=r*256+sc
//   Qr   u16 [65536][256]    @ 16777216     33,554,432   [p=(i*256+sc)][(h,d)]
//   Kr   u16 [65536][256]    @ 50331648     33,554,432   [p=(j*256+sc)][(h,d)]
//   Vtb  u16 [8][8192][256]  @ 83886080     33,554,432   [h][k*32+d][j]
//   Gb   u16 [65536][256]    @ 117440512    33,554,432   row = i*256+k
//   GOb  u16 [65536][256]    @ 150994944    33,554,432
//   Bp   f32 [8][256][256]   @ 184549376     2,097,152   bias projection
//   Ab   u16 [8][256][256]   @ 186646528     1,048,576   attn bf16
//   Wtb  u16 [4][256][128]   @ 187695104       262,144   W{q,k,v,g}^T [n][k]
//   Wotb u16 [128][256]      @ 187957248        65,536   Wo^T [c][e]
//   Lg2  f32 [8][8][256][256]@ 188022784    16,777,216   split-K logit slices
// total 204,800,000 B

typedef unsigned short u16;
typedef __attribute__((ext_vector_type(8))) short short8;
typedef __attribute__((ext_vector_type(4))) float float4v;

__device__ __forceinline__ u16 f2bf(float f) {
  unsigned int u = __float_as_uint(f);
  u += 0x7FFFu + ((u >> 16) & 1u);
  return (u16)(u >> 16);
}
__device__ __forceinline__ float bf2f(u16 h) {
  return __uint_as_float(((unsigned int)h) << 16);
}

// ---------------- K1: LayerNorm(pair) -> PNb (bf16) ----------------
__global__ __launch_bounds__(256) void k_ln(const float* __restrict__ x,
                                            const float* __restrict__ g,
                                            const float* __restrict__ b,
                                            u16* __restrict__ y) {
  int p = blockIdx.x * 4 + (threadIdx.x >> 6);
  int lane = threadIdx.x & 63;
  float2 xv = *(const float2*)(x + (size_t)p * 128 + lane * 2);
  float x0 = xv.x, x1 = xv.y;
  float s = x0 + x1, ss = x0 * x0 + x1 * x1;
#pragma unroll
  for (int off = 32; off; off >>= 1) {
    s += __shfl_xor(s, off);
    ss += __shfl_xor(ss, off);
  }
  float m = s * (1.0f / 128.0f);
  float v = ss * (1.0f / 128.0f) - m * m;
  float inv = rsqrtf(v + 1e-5f);
  float2 gv = *(const float2*)(g + lane * 2);
  float2 bv = *(const float2*)(b + lane * 2);
  float y0 = (x0 - m) * inv * gv.x + bv.x;
  float y1 = (x1 - m) * inv * gv.y + bv.y;
  unsigned int pk = (unsigned int)f2bf(y0) | ((unsigned int)f2bf(y1) << 16);
  *(unsigned int*)(y + (size_t)p * 128 + lane * 2) = pk;
}

// ---------------- K2: LayerNorm(bias) -> Bp (fp32) ----------------
// 8 threads per row: thread (row,h) loads 16 elems, 8-lane butterfly for
// stats, register-accumulates all 8 head partials, 8-lane butterfly reduce.
__global__ __launch_bounds__(256) void k_lnbias_bproj(const float* __restrict__ x,
                                                      const float* __restrict__ g,
                                                      const float* __restrict__ b,
                                                      const float* __restrict__ Wb,
                                                      float* __restrict__ Bp) {
  const int t = threadIdx.x;
  const int row = t >> 3, h = t & 7;
  const int p = blockIdx.x * 32 + row;
  const int r = p >> 8, sc = p & 255;
  const float* rp = x + (size_t)p * 128 + h * 16;
  float4 xv[4];
#pragma unroll
  for (int i = 0; i < 4; ++i) xv[i] = ((const float4*)rp)[i];
  float s = 0.f, ss = 0.f;
#pragma unroll
  for (int i = 0; i < 4; ++i) {
    s += (xv[i].x + xv[i].y) + (xv[i].z + xv[i].w);
    ss += (xv[i].x * xv[i].x + xv[i].y * xv[i].y) + (xv[i].z * xv[i].z + xv[i].w * xv[i].w);
  }
#pragma unroll
  for (int off = 1; off <= 4; off <<= 1) {
    s += __shfl_xor(s, off);
    ss += __shfl_xor(ss, off);
  }
  float m = s * (1.0f / 128.0f);
  float var = ss * (1.0f / 128.0f) - m * m;
  float inv = rsqrtf(var + 1e-5f);
  float part[8];
#pragma unroll
  for (int hh = 0; hh < 8; ++hh) part[hh] = 0.f;
  const float4* g4 = (const float4*)(g + h * 16);
  const float4* b4 = (const float4*)(b + h * 16);
#pragma unroll
  for (int i4 = 0; i4 < 4; ++i4) {
    float4 gv = g4[i4], bv = b4[i4];
    float xs[4] = {xv[i4].x, xv[i4].y, xv[i4].z, xv[i4].w};
    float gs[4] = {gv.x, gv.y, gv.z, gv.w};
    float bs[4] = {bv.x, bv.y, bv.z, bv.w};
#pragma unroll
    for (int q = 0; q < 4; ++q) {
      int k = h * 16 + i4 * 4 + q;
      float xn = (xs[q] - m) * inv * gs[q] + bs[q];
      float4 w0 = *(const float4*)(Wb + k * 8);
      float4 w1 = *(const float4*)(Wb + k * 8 + 4);
      part[0] += xn * w0.x;
      part[1] += xn * w0.y;
      part[2] += xn * w0.z;
      part[3] += xn * w0.w;
      part[4] += xn * w1.x;
      part[5] += xn * w1.y;
      part[6] += xn * w1.z;
      part[7] += xn * w1.w;
    }
  }
#pragma unroll
  for (int off = 1; off <= 4; off <<= 1) {
#pragma unroll
    for (int hh = 0; hh < 8; ++hh) part[hh] += __shfl_xor(part[hh], off);
  }
  float val = (h == 0) ? part[0]
            : (h == 1) ? part[1]
            : (h == 2) ? part[2]
            : (h == 3) ? part[3]
            : (h == 4) ? part[4]
            : (h == 5) ? part[5]
            : (h == 6) ? part[6]
                       : part[7];
  Bp[(size_t)h * 65536 + (size_t)sc * 256 + r] = val;
}

// ---------------- K3: weight convert/transpose to bf16 ----------------
__global__ __launch_bounds__(256) void k_wcvt(const float* __restrict__ Wq,
                                              const float* __restrict__ Wk,
                                              const float* __restrict__ Wv,
                                              const float* __restrict__ Wg,
                                              const float* __restrict__ Wo,
                                              u16* __restrict__ Wtb,
                                              u16* __restrict__ Wotb) {
  int idx = blockIdx.x * 256 + threadIdx.x;
  if (idx < 131072) {
    int w = idx >> 15, r = idx & 32767;
    int n = r >> 7, k = r & 127;  // out [n][k]
    const float* W = (w == 0) ? Wq : (w == 1) ? Wk : (w == 2) ? Wv : Wg;
    Wtb[(size_t)w * 32768 + n * 128 + k] = f2bf(W[k * 256 + n]);
  } else {
    int r = idx - 131072;  // Wo [256 e][128 c] -> Wotb[c][e]
    int c = r >> 8, e = r & 255;
    Wotb[c * 256 + e] = f2bf(Wo[e * 128 + c]);
  }
}

// ---------------- K4: Q/K/gate projections (MFMA, LDS-transpose epilogue) ----
// block = 128 consecutive PN rows (fixed r, sc in [s0,s0+128)). wave = 32 rows.
__global__ __launch_bounds__(256) void k_proj_qkg(const u16* __restrict__ PNb,
                                                  const u16* __restrict__ Wtb,
                                                  const float* __restrict__ bg,
                                                  u16* __restrict__ Qr,
                                                  u16* __restrict__ Kr,
                                                  u16* __restrict__ Gb) {
  __shared__ u16 sb[128 * 136];
  const int t = threadIdx.x;
  const int wid = t >> 6, lane = t & 63;
  const int mrow = lane & 15, quad = lane >> 4;
  const int p0 = blockIdx.x * 128;
  const int r = p0 >> 8, s0 = p0 & 255;
  short8 afr[2][4];
#pragma unroll
  for (int mt = 0; mt < 2; ++mt) {
    const u16* ar = PNb + (size_t)(p0 + wid * 32 + mt * 16 + mrow) * 128 + quad * 8;
#pragma unroll
    for (int kk = 0; kk < 4; ++kk) afr[mt][kk] = *(const short8*)(ar + kk * 32);
  }
#pragma unroll
  for (int wi = 0; wi < 3; ++wi) {
    const int wsel = (wi == 0) ? 0 : (wi == 1) ? 1 : 3;
    const u16* Wt = Wtb + (size_t)wsel * 32768;
    for (int half = 0; half < 2; ++half) {
#pragma unroll
      for (int nt8 = 0; nt8 < 8; ++nt8) {
        const int nt = half * 8 + nt8;
        float4v acc[2];
        acc[0] = (float4v){0.f, 0.f, 0.f, 0.f};
        acc[1] = (float4v){0.f, 0.f, 0.f, 0.f};
        const u16* br = Wt + (size_t)(nt * 16 + mrow) * 128 + quad * 8;
#pragma unroll
        for (int kk = 0; kk < 4; ++kk) {
          short8 bfr = *(const short8*)(br + kk * 32);
#pragma unroll
          for (int mt = 0; mt < 2; ++mt)
            acc[mt] = __builtin_amdgcn_mfma_f32_16x16x32_bf16(afr[mt][kk], bfr, acc[mt], 0, 0, 0);
        }
        const int n = nt * 16 + mrow;
        const float bgn = (wi == 2) ? bg[n] : 0.f;
#pragma unroll
        for (int mt = 0; mt < 2; ++mt) {
#pragma unroll
          for (int reg = 0; reg < 4; ++reg) {
            float v = acc[mt][reg];
            if (wi == 0) v *= 0.17677669529663687f;
            else if (wi == 1) v *= 0.0625f;
            else v = 1.f / (1.f + expf(-(v + bgn)));
            sb[(wid * 32 + mt * 16 + quad * 4 + reg) * 136 + nt8 * 16 + mrow] = f2bf(v);
          }
        }
      }
      __syncthreads();
      // 128 rows x 16 col-groups-of-8 = 2048 units; 256 thr x 8 iters.
      if (wi < 2) {
        u16* dst = (wi == 0) ? Qr : Kr;
#pragma unroll
        for (int it = 0; it < 8; ++it) {
          int u = it * 256 + t;
          int row = u >> 4, c8 = (u & 15) * 8;
          short8 vv = *(const short8*)&sb[row * 136 + c8];
          *(short8*)(dst + (size_t)(p0 + row) * 256 + half * 128 + c8) = vv;
        }
      } else {
#pragma unroll
        for (int it = 0; it < 8; ++it) {
          int u = it * 256 + t;
          int row = u >> 4, c8 = (u & 15) * 8;
          short8 vv = *(const short8*)&sb[row * 136 + c8];
          *(short8*)(Gb + ((size_t)(s0 + row) * 256 + r) * 256 + half * 128 + c8) = vv;
        }
      }
      __syncthreads();
    }
  }
}

// ---------------- K5: V projection (MFMA), tiled by fixed sc, 128 r-rows ----
__global__ __launch_bounds__(256) void k_projv(const u16* __restrict__ PNb,
                                               const u16* __restrict__ Wtb,
                                               u16* __restrict__ Vtb) {
  __shared__ u16 sb[128 * 136];
  const int t = threadIdx.x;
  const int wid = t >> 6, lane = t & 63;
  const int mrow = lane & 15, quad = lane >> 4;
  const int sc = blockIdx.x >> 1;
  const int r0 = (blockIdx.x & 1) * 128;
  short8 afr[2][4];
#pragma unroll
  for (int mt = 0; mt < 2; ++mt) {
    const int p = (r0 + wid * 32 + mt * 16 + mrow) * 256 + sc;
    const u16* ar = PNb + (size_t)p * 128 + quad * 8;
#pragma unroll
    for (int kk = 0; kk < 4; ++kk) afr[mt][kk] = *(const short8*)(ar + kk * 32);
  }
  const u16* Wt = Wtb + (size_t)2 * 32768;
  for (int half = 0; half < 2; ++half) {
#pragma unroll
    for (int nt8 = 0; nt8 < 8; ++nt8) {
      const int nt = half * 8 + nt8;
      float4v acc[2];
      acc[0] = (float4v){0.f, 0.f, 0.f, 0.f};
      acc[1] = (float4v){0.f, 0.f, 0.f, 0.f};
      const u16* br = Wt + (size_t)(nt * 16 + mrow) * 128 + quad * 8;
#pragma unroll
      for (int kk = 0; kk < 4; ++kk) {
        short8 bfr = *(const short8*)(br + kk * 32);
#pragma unroll
        for (int mt = 0; mt < 2; ++mt)
          acc[mt] = __builtin_amdgcn_mfma_f32_16x16x32_bf16(afr[mt][kk], bfr, acc[mt], 0, 0, 0);
      }
#pragma unroll
      for (int mt = 0; mt < 2; ++mt)
#pragma unroll
        for (int reg = 0; reg < 4; ++reg)
          sb[(wid * 32 + mt * 16 + quad * 4 + reg) * 136 + nt8 * 16 + mrow] =
              f2bf(acc[mt][reg]);
    }
    __syncthreads();
#pragma unroll
    for (int it = 0; it < 8; ++it) {
      int u = it * 256 + t;
      int c = u & 127, rg = u >> 7;
      short8 vv;
#pragma unroll
      for (int q = 0; q < 8; ++q) vv[q] = (short)sb[(rg * 8 + q) * 136 + c];
      int n = half * 128 + c;
      int h = n >> 5, d = n & 31;
      *(short8*)(Vtb + (size_t)h * 2097152 + (size_t)(sc * 32 + d) * 256 + r0 + rg * 8) = vv;
    }
    __syncthreads();
  }
}

// ---------------- K6: logits (MFMA), split-K plain stores to Lg2 ----------------
// grid (4 = 2 i-tiles x 2 j-tiles, 8 h, 8 kslabs). Lg2[z][h][i][j] partial sums.
__global__ __launch_bounds__(256) void k_logits_mfma(const u16* __restrict__ Qr,
                                                     const u16* __restrict__ Kr,
                                                     float* __restrict__ Lg2) {
  __shared__ u16 Qs[128 * 40];
  __shared__ u16 Ks[128 * 40];
  const int t = threadIdx.x;
  const int wid = t >> 6, lane = t & 63;
  const int mrow = lane & 15, quad = lane >> 4;
  const int i0 = (blockIdx.x >> 1) * 128, j0 = (blockIdx.x & 1) * 128;
  const int h = blockIdx.y;
  const int wi = wid >> 1, wj = wid & 1;
  float4v acc[4][4];
#pragma unroll
  for (int a = 0; a < 4; ++a)
#pragma unroll
    for (int bq = 0; bq < 4; ++bq) acc[a][bq] = (float4v){0.f, 0.f, 0.f, 0.f};

  for (int ck = 0; ck < 32; ++ck) {
    const int sc = blockIdx.z * 32 + ck;
    __syncthreads();
#pragma unroll
    for (int u = 0; u < 2; ++u) {
      int id = u * 256 + t;
      int rr = id >> 2, c8 = (id & 3) * 8;
      *(short8*)&Qs[rr * 40 + c8] =
          *(const short8*)(Qr + ((size_t)((i0 + rr) * 256 + sc)) * 256 + h * 32 + c8);
      *(short8*)&Ks[rr * 40 + c8] =
          *(const short8*)(Kr + ((size_t)((j0 + rr) * 256 + sc)) * 256 + h * 32 + c8);
    }
    __syncthreads();
    short8 afr[4], bfr[4];
#pragma unroll
    for (int mt = 0; mt < 4; ++mt)
      afr[mt] = *(const short8*)&Qs[(wi * 64 + mt * 16 + mrow) * 40 + quad * 8];
#pragma unroll
    for (int nn = 0; nn < 4; ++nn)
      bfr[nn] = *(const short8*)&Ks[(wj * 64 + nn * 16 + mrow) * 40 + quad * 8];
#pragma unroll
    for (int mt = 0; mt < 4; ++mt)
#pragma unroll
      for (int nn = 0; nn < 4; ++nn)
        acc[mt][nn] = __builtin_amdgcn_mfma_f32_16x16x32_bf16(afr[mt], bfr[nn], acc[mt][nn], 0, 0, 0);
  }
  float* slab = Lg2 + ((size_t)blockIdx.z * 8 + h) * 65536;
#pragma unroll
  for (int mt = 0; mt < 4; ++mt)
#pragma unroll
    for (int nn = 0; nn < 4; ++nn) {
      int j = j0 + wj * 64 + nn * 16 + mrow;
#pragma unroll
      for (int reg = 0; reg < 4; ++reg) {
        int i = i0 + wi * 64 + mt * 16 + quad * 4 + reg;
        slab[(size_t)i * 256 + j] = acc[mt][nn][reg];
      }
    }
}

// ---------------- K7: masked softmax over j (sum Bp + 8 slabs) -> Ab ----------
__global__ __launch_bounds__(256) void k_softmax(const float* __restrict__ Bp,
                                                 const float* __restrict__ Lg2,
                                                 const int* __restrict__ mask,
                                                 u16* __restrict__ Ab) {
  const int i = blockIdx.x, h = blockIdx.y;
  const int j = threadIdx.x;
  __shared__ float red[4], red2[4];
  const size_t off = (size_t)h * 65536 + (size_t)i * 256 + j;
  float x = Bp[off];
#pragma unroll
  for (int z = 0; z < 8; ++z) x += Lg2[(size_t)z * 524288 + off];
  bool mi = (mask[i] == 0);
  if (mi || (mask[j] == 0)) x = -1e9f;
  float mx = x;
#pragma unroll
  for (int off2 = 32; off2; off2 >>= 1) mx = fmaxf(mx, __shfl_xor(mx, off2));
  int wave = j >> 6;
  if ((j & 63) == 0) red[wave] = mx;
  __syncthreads();
  mx = fmaxf(fmaxf(red[0], red[1]), fmaxf(red[2], red[3]));
  float e = expf(x - mx);
  float sm = e;
#pragma unroll
  for (int off2 = 32; off2; off2 >>= 1) sm += __shfl_xor(sm, off2);
  if ((j & 63) == 0) red2[wave] = sm;
  __syncthreads();
  sm = red2[0] + red2[1] + red2[2] + red2[3];
  Ab[off] = f2bf(e / sm);
}

// ---------------- K8: AV (MFMA) + gate -> GOb (bf16) ----------------
__global__ __launch_bounds__(256) void k_av_mfma(const u16* __restrict__ Ab,
                                                 const u16* __restrict__ Vtb,
                                                 const u16* __restrict__ Gb,
                                                 u16* __restrict__ GOb) {
  __shared__ u16 As[64 * 264];
  const int t = threadIdx.x;
  const int wid = t >> 6, lane = t & 63;
  const int mrow = lane & 15, quad = lane >> 4;
  const int h = blockIdx.z;
  const int i0 = blockIdx.y * 64;
  const u16* ag = Ab + (size_t)h * 65536 + (size_t)i0 * 256;
#pragma unroll
  for (int u = 0; u < 8; ++u) {
    int id = u * 256 + t;
    int rr = id >> 5, c8 = (id & 31) * 8;
    *(short8*)&As[rr * 264 + c8] = *(const short8*)(ag + (size_t)rr * 256 + c8);
  }
  __syncthreads();
  const u16* vg = Vtb + (size_t)h * 2097152;
  for (int nt4 = 0; nt4 < 4; ++nt4) {
    const int nbase = blockIdx.x * 1024 + wid * 256 + nt4 * 64;
    float4v acc[4][4];
#pragma unroll
    for (int a = 0; a < 4; ++a)
#pragma unroll
      for (int bq = 0; bq < 4; ++bq) acc[a][bq] = (float4v){0.f, 0.f, 0.f, 0.f};
#pragma unroll
    for (int kk = 0; kk < 8; ++kk) {
      short8 afr[4], bfr[4];
#pragma unroll
      for (int mt = 0; mt < 4; ++mt)
        afr[mt] = *(const short8*)&As[(mt * 16 + mrow) * 264 + kk * 32 + quad * 8];
#pragma unroll
      for (int nn = 0; nn < 4; ++nn)
        bfr[nn] = *(const short8*)(vg + (size_t)(nbase + nn * 16 + mrow) * 256 + kk * 32 + quad * 8);
#pragma unroll
      for (int mt = 0; mt < 4; ++mt)
#pragma unroll
        for (int nn = 0; nn < 4; ++nn)
          acc[mt][nn] = __builtin_amdgcn_mfma_f32_16x16x32_bf16(afr[mt], bfr[nn], acc[mt][nn], 0, 0, 0);
    }
#pragma unroll
    for (int mt = 0; mt < 4; ++mt)
#pragma unroll
      for (int nn = 0; nn < 4; ++nn) {
        int n = nbase + nn * 16 + mrow;
        int kslot = n >> 5, d = n & 31;
        int e = h * 32 + d;
#pragma unroll
        for (int reg = 0; reg < 4; ++reg) {
          int i = i0 + mt * 16 + quad * 4 + reg;
          size_t idx = ((size_t)i * 256 + kslot) * 256 + e;
          float gv = bf2f(Gb[idx]);
          GOb[idx] = f2bf(acc[mt][nn][reg] * gv);
        }
      }
  }
}

// ---------------- K9: output proj (MFMA) + bias + transpose + mask ----------------
__global__ __launch_bounds__(256) void k_out_mfma(const u16* __restrict__ GOb,
                                                  const u16* __restrict__ Wotb,
                                                  const float* __restrict__ bo,
                                                  const int* __restrict__ mask,
                                                  float* __restrict__ out) {
  const int wid = threadIdx.x >> 6, lane = threadIdx.x & 63;
  const int mrow = lane & 15, quad = lane >> 4;
  const int m0 = blockIdx.x * 128 + wid * 32;
  short8 afr[2][8];
#pragma unroll
  for (int mt = 0; mt < 2; ++mt) {
    const u16* ar = GOb + (size_t)(m0 + mt * 16 + mrow) * 256 + quad * 8;
#pragma unroll
    for (int kk = 0; kk < 8; ++kk) afr[mt][kk] = *(const short8*)(ar + kk * 32);
  }
  for (int nt = 0; nt < 8; ++nt) {
    float4v acc[2];
    acc[0] = (float4v){0.f, 0.f, 0.f, 0.f};
    acc[1] = (float4v){0.f, 0.f, 0.f, 0.f};
    const u16* br = Wotb + (size_t)(nt * 16 + mrow) * 256 + quad * 8;
#pragma unroll
    for (int kk = 0; kk < 8; ++kk) {
      short8 bfr = *(const short8*)(br + kk * 32);
#pragma unroll
      for (int mt = 0; mt < 2; ++mt)
        acc[mt] = __builtin_amdgcn_mfma_f32_16x16x32_bf16(afr[mt][kk], bfr, acc[mt], 0, 0, 0);
    }
    const int c = nt * 16 + mrow;
    float bov = bo[c];
#pragma unroll
    for (int mt = 0; mt < 2; ++mt) {
#pragma unroll
      for (int reg = 0; reg < 4; ++reg) {
        int m = m0 + mt * 16 + quad * 4 + reg;  // = i*256 + k
        int i = m >> 8, kq = m & 255;
        float v = acc[mt][reg] + bov;
        bool z = (mask[i] == 0) || (mask[kq] == 0);
        out[((size_t)kq * 256 + i) * 128 + c] = z ? 0.f : v;
      }
    }
  }
}

extern "C" void kernel_launch(void* const* d_in, const int* in_sizes, int n_in,
                              void* d_out, int out_size, void* d_ws, size_t ws_size,
                              hipStream_t stream) {
  const float* pair = (const float*)d_in[0];
  const float* bias = (const float*)d_in[1];
  const int* mask = (const int*)d_in[2];
  const float* g_pair = (const float*)d_in[3];
  const float* b_pair = (const float*)d_in[4];
  const float* g_bias = (const float*)d_in[5];
  const float* b_bias = (const float*)d_in[6];
  const float* Wq = (const float*)d_in[7];
  const float* Wk = (const float*)d_in[8];
  const float* Wv = (const float*)d_in[9];
  const float* Wb = (const float*)d_in[10];
  const float* Wg = (const float*)d_in[11];
  const float* bg = (const float*)d_in[12];
  const float* Wo = (const float*)d_in[13];
  const float* bo = (const float*)d_in[14];
  float* out = (float*)d_out;
  char* ws = (char*)d_ws;

  u16* PNb = (u16*)(ws + 0);
  u16* Qr = (u16*)(ws + 16777216);
  u16* Kr = (u16*)(ws + 50331648);
  u16* Vtb = (u16*)(ws + 83886080);
  u16* Gb = (u16*)(ws + 117440512);
  u16* GOb = (u16*)(ws + 150994944);
  float* Bp = (float*)(ws + 184549376);
  u16* Ab = (u16*)(ws + 186646528);
  u16* Wtb = (u16*)(ws + 187695104);
  u16* Wotb = (u16*)(ws + 187957248);
  float* Lg2 = (float*)(ws + 188022784);

  k_ln<<<16384, 256, 0, stream>>>(pair, g_pair, b_pair, PNb);
  k_wcvt<<<640, 256, 0, stream>>>(Wq, Wk, Wv, Wg, Wo, Wtb, Wotb);
  k_lnbias_bproj<<<2048, 256, 0, stream>>>(bias, g_bias, b_bias, Wb, Bp);
  k_proj_qkg<<<512, 256, 0, stream>>>(PNb, Wtb, bg, Qr, Kr, Gb);
  k_projv<<<512, 256, 0, stream>>>(PNb, Wtb, Vtb);
  k_logits_mfma<<<dim3(4, 8, 8), 256, 0, stream>>>(Qr, Kr, Lg2);
  k_softmax<<<dim3(256, 8), 256, 0, stream>>>(Bp, Lg2, mask, Ab);
  k_av_mfma<<<dim3(8, 4, 8), 256, 0, stream>>>(Ab, Vtb, Gb, GOb);
  k_out_mfma<<<512, 256, 0, stream>>>(GOb, Wotb, bo, mask, out);
}

// Round 7
// 361.769 us; speedup vs baseline: 2.6700x; 1.0293x over previous
//
#include <hip/hip_runtime.h>
#include <math.h>

// B=1, L=256, DP=128, DB=128, H=8, DH=32, H*DH=256
// bf16 MFMA 16x16x32; all global stores wide/contiguous via LDS transpose
// epilogues. NO atomics / cross-kernel RMW: every ws cell is written by
// exactly one kernel (plain stores) before any reader -> bit-deterministic.
//
// Fragment layouts (HW-verified):
//   A-frag: lane holds A[m=lane&15][k=(lane>>4)*8+j], j=0..7 (16B)
//   B-frag: lane holds B[k=(lane>>4)*8+j][n=lane&15]
//   D:      lane holds D[row=(lane>>4)*4+reg][col=lane&15]
//
// Workspace (byte offsets):
//   PNb  u16 [65536][128]    @ 0            16,777,216   LN(pair), row p=r*256+sc
//   Qr   u16 [65536][256]    @ 16777216     33,554,432   [p=(i*256+sc)][(h,d)]
//   Kr   u16 [65536][256]    @ 50331648     33,554,432   [p=(j*256+sc)][(h,d)]
//   Vtb  u16 [8][8192][256]  @ 83886080     33,554,432   [h][k*32+d][j]
//   Gb   u16 [65536][256]    @ 117440512    33,554,432   row = i*256+k
//   GOb  u16 [65536][256]    @ 150994944    33,554,432
//   Bp   f32 [8][256][256]   @ 184549376     2,097,152   bias projection
//   Ab   u16 [8][256][256]   @ 186646528     1,048,576   attn bf16
//   Wtb  u16 [4][256][128]   @ 187695104       262,144   W{q,k,v,g}^T [n][k]
//   Wotb u16 [128][256]      @ 187957248        65,536   Wo^T [c][e]
//   Lg2  f32 [8][8][256][256]@ 188022784    16,777,216   split-K logit slices
// total 204,800,000 B

typedef unsigned short u16;
typedef __attribute__((ext_vector_type(8))) short short8;
typedef __attribute__((ext_vector_type(4))) float float4v;

__device__ __forceinline__ u16 f2bf(float f) {
  unsigned int u = __float_as_uint(f);
  u += 0x7FFFu + ((u >> 16) & 1u);
  return (u16)(u >> 16);
}
__device__ __forceinline__ float bf2f(u16 h) {
  return __uint_as_float(((unsigned int)h) << 16);
}

// ---------------- K1: LayerNorm(pair) -> PNb (bf16) ----------------
__global__ __launch_bounds__(256) void k_ln(const float* __restrict__ x,
                                            const float* __restrict__ g,
                                            const float* __restrict__ b,
                                            u16* __restrict__ y) {
  int p = blockIdx.x * 4 + (threadIdx.x >> 6);
  int lane = threadIdx.x & 63;
  float2 xv = *(const float2*)(x + (size_t)p * 128 + lane * 2);
  float x0 = xv.x, x1 = xv.y;
  float s = x0 + x1, ss = x0 * x0 + x1 * x1;
#pragma unroll
  for (int off = 32; off; off >>= 1) {
    s += __shfl_xor(s, off);
    ss += __shfl_xor(ss, off);
  }
  float m = s * (1.0f / 128.0f);
  float v = ss * (1.0f / 128.0f) - m * m;
  float inv = rsqrtf(v + 1e-5f);
  float2 gv = *(const float2*)(g + lane * 2);
  float2 bv = *(const float2*)(b + lane * 2);
  float y0 = (x0 - m) * inv * gv.x + bv.x;
  float y1 = (x1 - m) * inv * gv.y + bv.y;
  unsigned int pk = (unsigned int)f2bf(y0) | ((unsigned int)f2bf(y1) << 16);
  *(unsigned int*)(y + (size_t)p * 128 + lane * 2) = pk;
}

// ---------------- K2: LayerNorm(bias) -> Bp (fp32) ----------------
__global__ __launch_bounds__(256) void k_lnbias_bproj(const float* __restrict__ x,
                                                      const float* __restrict__ g,
                                                      const float* __restrict__ b,
                                                      const float* __restrict__ Wb,
                                                      float* __restrict__ Bp) {
  const int t = threadIdx.x;
  const int row = t >> 3, h = t & 7;
  const int p = blockIdx.x * 32 + row;
  const int r = p >> 8, sc = p & 255;
  const float* rp = x + (size_t)p * 128 + h * 16;
  float4 xv[4];
#pragma unroll
  for (int i = 0; i < 4; ++i) xv[i] = ((const float4*)rp)[i];
  float s = 0.f, ss = 0.f;
#pragma unroll
  for (int i = 0; i < 4; ++i) {
    s += (xv[i].x + xv[i].y) + (xv[i].z + xv[i].w);
    ss += (xv[i].x * xv[i].x + xv[i].y * xv[i].y) + (xv[i].z * xv[i].z + xv[i].w * xv[i].w);
  }
#pragma unroll
  for (int off = 1; off <= 4; off <<= 1) {
    s += __shfl_xor(s, off);
    ss += __shfl_xor(ss, off);
  }
  float m = s * (1.0f / 128.0f);
  float var = ss * (1.0f / 128.0f) - m * m;
  float inv = rsqrtf(var + 1e-5f);
  float part[8];
#pragma unroll
  for (int hh = 0; hh < 8; ++hh) part[hh] = 0.f;
  const float4* g4 = (const float4*)(g + h * 16);
  const float4* b4 = (const float4*)(b + h * 16);
#pragma unroll
  for (int i4 = 0; i4 < 4; ++i4) {
    float4 gv = g4[i4], bv = b4[i4];
    float xs[4] = {xv[i4].x, xv[i4].y, xv[i4].z, xv[i4].w};
    float gs[4] = {gv.x, gv.y, gv.z, gv.w};
    float bs[4] = {bv.x, bv.y, bv.z, bv.w};
#pragma unroll
    for (int q = 0; q < 4; ++q) {
      int k = h * 16 + i4 * 4 + q;
      float xn = (xs[q] - m) * inv * gs[q] + bs[q];
      float4 w0 = *(const float4*)(Wb + k * 8);
      float4 w1 = *(const float4*)(Wb + k * 8 + 4);
      part[0] += xn * w0.x;
      part[1] += xn * w0.y;
      part[2] += xn * w0.z;
      part[3] += xn * w0.w;
      part[4] += xn * w1.x;
      part[5] += xn * w1.y;
      part[6] += xn * w1.z;
      part[7] += xn * w1.w;
    }
  }
#pragma unroll
  for (int off = 1; off <= 4; off <<= 1) {
#pragma unroll
    for (int hh = 0; hh < 8; ++hh) part[hh] += __shfl_xor(part[hh], off);
  }
  float val = (h == 0) ? part[0]
            : (h == 1) ? part[1]
            : (h == 2) ? part[2]
            : (h == 3) ? part[3]
            : (h == 4) ? part[4]
            : (h == 5) ? part[5]
            : (h == 6) ? part[6]
                       : part[7];
  Bp[(size_t)h * 65536 + (size_t)sc * 256 + r] = val;
}

// ---------------- K3: weight convert/transpose to bf16 ----------------
__global__ __launch_bounds__(256) void k_wcvt(const float* __restrict__ Wq,
                                              const float* __restrict__ Wk,
                                              const float* __restrict__ Wv,
                                              const float* __restrict__ Wg,
                                              const float* __restrict__ Wo,
                                              u16* __restrict__ Wtb,
                                              u16* __restrict__ Wotb) {
  int idx = blockIdx.x * 256 + threadIdx.x;
  if (idx < 131072) {
    int w = idx >> 15, r = idx & 32767;
    int n = r >> 7, k = r & 127;  // out [n][k]
    const float* W = (w == 0) ? Wq : (w == 1) ? Wk : (w == 2) ? Wv : Wg;
    Wtb[(size_t)w * 32768 + n * 128 + k] = f2bf(W[k * 256 + n]);
  } else {
    int r = idx - 131072;  // Wo [256 e][128 c] -> Wotb[c][e]
    int c = r >> 8, e = r & 255;
    Wotb[c * 256 + e] = f2bf(Wo[e * 128 + c]);
  }
}

// ---------------- K4 v2: Q/K/gate projections, B-resident streaming ----------
// grid (128 row-stripes, 4 col-quarters, 3 weights {Q,K,G}); 256 thr / 4 waves.
// B-frags (64 cols x K=128) live in registers for the whole kernel; wave
// streams 4 x 32-row tiles (block: 4 x 128 rows of its 512-row stripe).
__global__ __launch_bounds__(256) void k_proj_qkg(const u16* __restrict__ PNb,
                                                  const u16* __restrict__ Wtb,
                                                  const float* __restrict__ bg,
                                                  u16* __restrict__ Qr,
                                                  u16* __restrict__ Kr,
                                                  u16* __restrict__ Gb) {
  __shared__ u16 sb[128 * 72];
  const int t = threadIdx.x;
  const int wid = t >> 6, lane = t & 63;
  const int mrow = lane & 15, quad = lane >> 4;
  const int stripe = blockIdx.x;   // 0..127 -> rows [stripe*512, +512)
  const int n0 = blockIdx.y * 64;  // col quarter
  const int wsel3 = blockIdx.z;    // 0:Q 1:K 2:G
  const int wsel = (wsel3 == 2) ? 3 : wsel3;
  const u16* Wt = Wtb + (size_t)wsel * 32768;

  short8 bfr[4][4];
#pragma unroll
  for (int nt = 0; nt < 4; ++nt)
#pragma unroll
    for (int kk = 0; kk < 4; ++kk)
      bfr[nt][kk] = *(const short8*)(Wt + (size_t)(n0 + nt * 16 + mrow) * 128 + kk * 32 + quad * 8);

  float bgv[4];
#pragma unroll
  for (int nt = 0; nt < 4; ++nt) bgv[nt] = bg[n0 + nt * 16 + mrow];

  for (int it = 0; it < 4; ++it) {
    const int pb = stripe * 512 + it * 128;
    const int pw = pb + wid * 32;
    short8 afr[2][4];
#pragma unroll
    for (int mt = 0; mt < 2; ++mt)
#pragma unroll
      for (int kk = 0; kk < 4; ++kk)
        afr[mt][kk] =
            *(const short8*)(PNb + (size_t)(pw + mt * 16 + mrow) * 128 + kk * 32 + quad * 8);
    float4v acc[2][4];
#pragma unroll
    for (int mt = 0; mt < 2; ++mt)
#pragma unroll
      for (int nt = 0; nt < 4; ++nt) acc[mt][nt] = (float4v){0.f, 0.f, 0.f, 0.f};
#pragma unroll
    for (int kk = 0; kk < 4; ++kk)
#pragma unroll
      for (int mt = 0; mt < 2; ++mt)
#pragma unroll
        for (int nt = 0; nt < 4; ++nt)
          acc[mt][nt] = __builtin_amdgcn_mfma_f32_16x16x32_bf16(afr[mt][kk], bfr[nt][kk],
                                                                acc[mt][nt], 0, 0, 0);
#pragma unroll
    for (int mt = 0; mt < 2; ++mt)
#pragma unroll
      for (int nt = 0; nt < 4; ++nt)
#pragma unroll
        for (int reg = 0; reg < 4; ++reg) {
          float v = acc[mt][nt][reg];
          if (wsel3 == 0) v *= 0.17677669529663687f;
          else if (wsel3 == 1) v *= 0.0625f;
          else v = 1.f / (1.f + expf(-(v + bgv[nt])));
          sb[(wid * 32 + mt * 16 + quad * 4 + reg) * 72 + nt * 16 + mrow] = f2bf(v);
        }
    __syncthreads();
    // store 128 rows x 64 cols: 1024 units of 8 u16
#pragma unroll
    for (int u4 = 0; u4 < 4; ++u4) {
      int u = u4 * 256 + t;
      int row = u >> 3, c8 = (u & 7) * 8;
      short8 vv = *(const short8*)&sb[row * 72 + c8];
      int p = pb + row;
      if (wsel3 == 0) {
        *(short8*)(Qr + (size_t)p * 256 + n0 + c8) = vv;
      } else if (wsel3 == 1) {
        *(short8*)(Kr + (size_t)p * 256 + n0 + c8) = vv;
      } else {
        int r = p >> 8, sc = p & 255;
        *(short8*)(Gb + ((size_t)sc * 256 + r) * 256 + n0 + c8) = vv;
      }
    }
    __syncthreads();
  }
}

// ---------------- K5: V projection (MFMA), tiled by fixed sc, 128 r-rows ----
__global__ __launch_bounds__(256) void k_projv(const u16* __restrict__ PNb,
                                               const u16* __restrict__ Wtb,
                                               u16* __restrict__ Vtb) {
  __shared__ u16 sb[128 * 136];
  const int t = threadIdx.x;
  const int wid = t >> 6, lane = t & 63;
  const int mrow = lane & 15, quad = lane >> 4;
  const int sc = blockIdx.x >> 1;
  const int r0 = (blockIdx.x & 1) * 128;
  short8 afr[2][4];
#pragma unroll
  for (int mt = 0; mt < 2; ++mt) {
    const int p = (r0 + wid * 32 + mt * 16 + mrow) * 256 + sc;
    const u16* ar = PNb + (size_t)p * 128 + quad * 8;
#pragma unroll
    for (int kk = 0; kk < 4; ++kk) afr[mt][kk] = *(const short8*)(ar + kk * 32);
  }
  const u16* Wt = Wtb + (size_t)2 * 32768;
  for (int half = 0; half < 2; ++half) {
#pragma unroll
    for (int nt8 = 0; nt8 < 8; ++nt8) {
      const int nt = half * 8 + nt8;
      float4v acc[2];
      acc[0] = (float4v){0.f, 0.f, 0.f, 0.f};
      acc[1] = (float4v){0.f, 0.f, 0.f, 0.f};
      const u16* br = Wt + (size_t)(nt * 16 + mrow) * 128 + quad * 8;
#pragma unroll
      for (int kk = 0; kk < 4; ++kk) {
        short8 bfr = *(const short8*)(br + kk * 32);
#pragma unroll
        for (int mt = 0; mt < 2; ++mt)
          acc[mt] = __builtin_amdgcn_mfma_f32_16x16x32_bf16(afr[mt][kk], bfr, acc[mt], 0, 0, 0);
      }
#pragma unroll
      for (int mt = 0; mt < 2; ++mt)
#pragma unroll
        for (int reg = 0; reg < 4; ++reg)
          sb[(wid * 32 + mt * 16 + quad * 4 + reg) * 136 + nt8 * 16 + mrow] =
              f2bf(acc[mt][reg]);
    }
    __syncthreads();
#pragma unroll
    for (int it = 0; it < 8; ++it) {
      int u = it * 256 + t;
      int c = u & 127, rg = u >> 7;
      short8 vv;
#pragma unroll
      for (int q = 0; q < 8; ++q) vv[q] = (short)sb[(rg * 8 + q) * 136 + c];
      int n = half * 128 + c;
      int h = n >> 5, d = n & 31;
      *(short8*)(Vtb + (size_t)h * 2097152 + (size_t)(sc * 32 + d) * 256 + r0 + rg * 8) = vv;
    }
    __syncthreads();
  }
}

// ---------------- K6: logits (MFMA), split-K plain stores to Lg2 ----------------
__global__ __launch_bounds__(256) void k_logits_mfma(const u16* __restrict__ Qr,
                                                     const u16* __restrict__ Kr,
                                                     float* __restrict__ Lg2) {
  __shared__ u16 Qs[128 * 40];
  __shared__ u16 Ks[128 * 40];
  const int t = threadIdx.x;
  const int wid = t >> 6, lane = t & 63;
  const int mrow = lane & 15, quad = lane >> 4;
  const int i0 = (blockIdx.x >> 1) * 128, j0 = (blockIdx.x & 1) * 128;
  const int h = blockIdx.y;
  const int wi = wid >> 1, wj = wid & 1;
  float4v acc[4][4];
#pragma unroll
  for (int a = 0; a < 4; ++a)
#pragma unroll
    for (int bq = 0; bq < 4; ++bq) acc[a][bq] = (float4v){0.f, 0.f, 0.f, 0.f};

  for (int ck = 0; ck < 32; ++ck) {
    const int sc = blockIdx.z * 32 + ck;
    __syncthreads();
#pragma unroll
    for (int u = 0; u < 2; ++u) {
      int id = u * 256 + t;
      int rr = id >> 2, c8 = (id & 3) * 8;
      *(short8*)&Qs[rr * 40 + c8] =
          *(const short8*)(Qr + ((size_t)((i0 + rr) * 256 + sc)) * 256 + h * 32 + c8);
      *(short8*)&Ks[rr * 40 + c8] =
          *(const short8*)(Kr + ((size_t)((j0 + rr) * 256 + sc)) * 256 + h * 32 + c8);
    }
    __syncthreads();
    short8 afr[4], bfr[4];
#pragma unroll
    for (int mt = 0; mt < 4; ++mt)
      afr[mt] = *(const short8*)&Qs[(wi * 64 + mt * 16 + mrow) * 40 + quad * 8];
#pragma unroll
    for (int nn = 0; nn < 4; ++nn)
      bfr[nn] = *(const short8*)&Ks[(wj * 64 + nn * 16 + mrow) * 40 + quad * 8];
#pragma unroll
    for (int mt = 0; mt < 4; ++mt)
#pragma unroll
      for (int nn = 0; nn < 4; ++nn)
        acc[mt][nn] = __builtin_amdgcn_mfma_f32_16x16x32_bf16(afr[mt], bfr[nn], acc[mt][nn], 0, 0, 0);
  }
  float* slab = Lg2 + ((size_t)blockIdx.z * 8 + h) * 65536;
#pragma unroll
  for (int mt = 0; mt < 4; ++mt)
#pragma unroll
    for (int nn = 0; nn < 4; ++nn) {
      int j = j0 + wj * 64 + nn * 16 + mrow;
#pragma unroll
      for (int reg = 0; reg < 4; ++reg) {
        int i = i0 + wi * 64 + mt * 16 + quad * 4 + reg;
        slab[(size_t)i * 256 + j] = acc[mt][nn][reg];
      }
    }
}

// ---------------- K7: masked softmax over j (sum Bp + 8 slabs) -> Ab ----------
__global__ __launch_bounds__(256) void k_softmax(const float* __restrict__ Bp,
                                                 const float* __restrict__ Lg2,
                                                 const int* __restrict__ mask,
                                                 u16* __restrict__ Ab) {
  const int i = blockIdx.x, h = blockIdx.y;
  const int j = threadIdx.x;
  __shared__ float red[4], red2[4];
  const size_t off = (size_t)h * 65536 + (size_t)i * 256 + j;
  float x = Bp[off];
#pragma unroll
  for (int z = 0; z < 8; ++z) x += Lg2[(size_t)z * 524288 + off];
  bool mi = (mask[i] == 0);
  if (mi || (mask[j] == 0)) x = -1e9f;
  float mx = x;
#pragma unroll
  for (int off2 = 32; off2; off2 >>= 1) mx = fmaxf(mx, __shfl_xor(mx, off2));
  int wave = j >> 6;
  if ((j & 63) == 0) red[wave] = mx;
  __syncthreads();
  mx = fmaxf(fmaxf(red[0], red[1]), fmaxf(red[2], red[3]));
  float e = expf(x - mx);
  float sm = e;
#pragma unroll
  for (int off2 = 32; off2; off2 >>= 1) sm += __shfl_xor(sm, off2);
  if ((j & 63) == 0) red2[wave] = sm;
  __syncthreads();
  sm = red2[0] + red2[1] + red2[2] + red2[3];
  Ab[off] = f2bf(e / sm);
}

// ---------------- K8: AV (MFMA) + gate -> GOb (bf16) ----------------
__global__ __launch_bounds__(256) void k_av_mfma(const u16* __restrict__ Ab,
                                                 const u16* __restrict__ Vtb,
                                                 const u16* __restrict__ Gb,
                                                 u16* __restrict__ GOb) {
  __shared__ u16 As[64 * 264];
  const int t = threadIdx.x;
  const int wid = t >> 6, lane = t & 63;
  const int mrow = lane & 15, quad = lane >> 4;
  const int h = blockIdx.z;
  const int i0 = blockIdx.y * 64;
  const u16* ag = Ab + (size_t)h * 65536 + (size_t)i0 * 256;
#pragma unroll
  for (int u = 0; u < 8; ++u) {
    int id = u * 256 + t;
    int rr = id >> 5, c8 = (id & 31) * 8;
    *(short8*)&As[rr * 264 + c8] = *(const short8*)(ag + (size_t)rr * 256 + c8);
  }
  __syncthreads();
  const u16* vg = Vtb + (size_t)h * 2097152;
  for (int nt4 = 0; nt4 < 4; ++nt4) {
    const int nbase = blockIdx.x * 1024 + wid * 256 + nt4 * 64;
    float4v acc[4][4];
#pragma unroll
    for (int a = 0; a < 4; ++a)
#pragma unroll
      for (int bq = 0; bq < 4; ++bq) acc[a][bq] = (float4v){0.f, 0.f, 0.f, 0.f};
#pragma unroll
    for (int kk = 0; kk < 8; ++kk) {
      short8 afr[4], bfr[4];
#pragma unroll
      for (int mt = 0; mt < 4; ++mt)
        afr[mt] = *(const short8*)&As[(mt * 16 + mrow) * 264 + kk * 32 + quad * 8];
#pragma unroll
      for (int nn = 0; nn < 4; ++nn)
        bfr[nn] = *(const short8*)(vg + (size_t)(nbase + nn * 16 + mrow) * 256 + kk * 32 + quad * 8);
#pragma unroll
      for (int mt = 0; mt < 4; ++mt)
#pragma unroll
        for (int nn = 0; nn < 4; ++nn)
          acc[mt][nn] = __builtin_amdgcn_mfma_f32_16x16x32_bf16(afr[mt], bfr[nn], acc[mt][nn], 0, 0, 0);
    }
#pragma unroll
    for (int mt = 0; mt < 4; ++mt)
#pragma unroll
      for (int nn = 0; nn < 4; ++nn) {
        int n = nbase + nn * 16 + mrow;
        int kslot = n >> 5, d = n & 31;
        int e = h * 32 + d;
#pragma unroll
        for (int reg = 0; reg < 4; ++reg) {
          int i = i0 + mt * 16 + quad * 4 + reg;
          size_t idx = ((size_t)i * 256 + kslot) * 256 + e;
          float gv = bf2f(Gb[idx]);
          GOb[idx] = f2bf(acc[mt][nn][reg] * gv);
        }
      }
  }
}

// ---------------- K9: output proj (MFMA) + bias + transpose + mask ----------------
__global__ __launch_bounds__(256) void k_out_mfma(const u16* __restrict__ GOb,
                                                  const u16* __restrict__ Wotb,
                                                  const float* __restrict__ bo,
                                                  const int* __restrict__ mask,
                                                  float* __restrict__ out) {
  const int wid = threadIdx.x >> 6, lane = threadIdx.x & 63;
  const int mrow = lane & 15, quad = lane >> 4;
  const int m0 = blockIdx.x * 128 + wid * 32;
  short8 afr[2][8];
#pragma unroll
  for (int mt = 0; mt < 2; ++mt) {
    const u16* ar = GOb + (size_t)(m0 + mt * 16 + mrow) * 256 + quad * 8;
#pragma unroll
    for (int kk = 0; kk < 8; ++kk) afr[mt][kk] = *(const short8*)(ar + kk * 32);
  }
  for (int nt = 0; nt < 8; ++nt) {
    float4v acc[2];
    acc[0] = (float4v){0.f, 0.f, 0.f, 0.f};
    acc[1] = (float4v){0.f, 0.f, 0.f, 0.f};
    const u16* br = Wotb + (size_t)(nt * 16 + mrow) * 256 + quad * 8;
#pragma unroll
    for (int kk = 0; kk < 8; ++kk) {
      short8 bfr = *(const short8*)(br + kk * 32);
#pragma unroll
      for (int mt = 0; mt < 2; ++mt)
        acc[mt] = __builtin_amdgcn_mfma_f32_16x16x32_bf16(afr[mt][kk], bfr, acc[mt], 0, 0, 0);
    }
    const int c = nt * 16 + mrow;
    float bov = bo[c];
#pragma unroll
    for (int mt = 0; mt < 2; ++mt) {
#pragma unroll
      for (int reg = 0; reg < 4; ++reg) {
        int m = m0 + mt * 16 + quad * 4 + reg;  // = i*256 + k
        int i = m >> 8, kq = m & 255;
        float v = acc[mt][reg] + bov;
        bool z = (mask[i] == 0) || (mask[kq] == 0);
        out[((size_t)kq * 256 + i) * 128 + c] = z ? 0.f : v;
      }
    }
  }
}

extern "C" void kernel_launch(void* const* d_in, const int* in_sizes, int n_in,
                              void* d_out, int out_size, void* d_ws, size_t ws_size,
                              hipStream_t stream) {
  const float* pair = (const float*)d_in[0];
  const float* bias = (const float*)d_in[1];
  const int* mask = (const int*)d_in[2];
  const float* g_pair = (const float*)d_in[3];
  const float* b_pair = (const float*)d_in[4];
  const float* g_bias = (const float*)d_in[5];
  const float* b_bias = (const float*)d_in[6];
  const float* Wq = (const float*)d_in[7];
  const float* Wk = (const float*)d_in[8];
  const float* Wv = (const float*)d_in[9];
  const float* Wb = (const float*)d_in[10];
  const float* Wg = (const float*)d_in[11];
  const float* bg = (const float*)d_in[12];
  const float* Wo = (const float*)d_in[13];
  const float* bo = (const float*)d_in[14];
  float* out = (float*)d_out;
  char* ws = (char*)d_ws;

  u16* PNb = (u16*)(ws + 0);
  u16* Qr = (u16*)(ws + 16777216);
  u16* Kr = (u16*)(ws + 50331648);
  u16* Vtb = (u16*)(ws + 83886080);
  u16* Gb = (u16*)(ws + 117440512);
  u16* GOb = (u16*)(ws + 150994944);
  float* Bp = (float*)(ws + 184549376);
  u16* Ab = (u16*)(ws + 186646528);
  u16* Wtb = (u16*)(ws + 187695104);
  u16* Wotb = (u16*)(ws + 187957248);
  float* Lg2 = (float*)(ws + 188022784);

  k_ln<<<16384, 256, 0, stream>>>(pair, g_pair, b_pair, PNb);
  k_wcvt<<<640, 256, 0, stream>>>(Wq, Wk, Wv, Wg, Wo, Wtb, Wotb);
  k_lnbias_bproj<<<2048, 256, 0, stream>>>(bias, g_bias, b_bias, Wb, Bp);
  k_proj_qkg<<<dim3(128, 4, 3), 256, 0, stream>>>(PNb, Wtb, bg, Qr, Kr, Gb);
  k_projv<<<512, 256, 0, stream>>>(PNb, Wtb, Vtb);
  k_logits_mfma<<<dim3(4, 8, 8), 256, 0, stream>>>(Qr, Kr, Lg2);
  k_softmax<<<dim3(256, 8), 256, 0, stream>>>(Bp, Lg2, mask, Ab);
  k_av_mfma<<<dim3(8, 4, 8), 256, 0, stream>>>(Ab, Vtb, Gb, GOb);
  k_out_mfma<<<512, 256, 0, stream>>>(GOb, Wotb, bo, mask, out);
}

// Round 8
// 338.193 us; speedup vs baseline: 2.8561x; 1.0697x over previous
//
#include <hip/hip_runtime.h>
#include <math.h>

// B=1, L=256, DP=128, DB=128, H=8, DH=32, H*DH=256
// bf16 MFMA 16x16x32. Q/K/G use a 4-row-tiled layout X4[(p>>2)][n][p&3] so
// the MFMA D-fragment (4 consecutive rows per lane) packs into single 8B
// stores -> no LDS transpose, no barriers in the projection kernel.
// NO atomics / cross-kernel RMW anywhere: bit-deterministic across replays.
//
// Fragment layouts (HW-verified):
//   A-frag: lane holds A[m=lane&15][k=(lane>>4)*8+j], j=0..7 (16B)
//   B-frag: lane holds B[k=(lane>>4)*8+j][n=lane&15]
//   D:      lane holds D[row=(lane>>4)*4+reg][col=lane&15]
//
// Workspace (byte offsets):
//   PNb  u16 [65536][128]     @ 0            16,777,216   LN(pair), row p=r*256+sc
//   Qr4  u16 tiled [16384][256][4] @ 16777216 33,554,432  (p>>2, n, p&3), p=(i,sc)
//   Kr4  u16 tiled             @ 50331648    33,554,432
//   Vtb  u16 [8][8192][256]   @ 83886080     33,554,432   [h][k*32+d][j]
//   G2   u16 tiled             @ 117440512   33,554,432   p = r*256+sc (= kslot*256+i)
//   GOb  u16 [65536][256]     @ 150994944    33,554,432   row = i*256+k
//   Bp   f32 [8][256][256]    @ 184549376     2,097,152
//   Ab   u16 [8][256][256]    @ 186646528     1,048,576
//   Wtb  u16 [4][256][128]    @ 187695104       262,144   W{q,k,v,g}^T [n][k]
//   Wotb u16 [128][256]       @ 187957248        65,536   Wo^T [c][e]
//   Lg2  f32 [16][8][256][256]@ 188022784    33,554,432   split-K logit slices
// total 221,577,216 B

typedef unsigned short u16;
typedef __attribute__((ext_vector_type(8))) short short8;
typedef __attribute__((ext_vector_type(4))) short short4v;
typedef __attribute__((ext_vector_type(4))) float float4v;

__device__ __forceinline__ u16 f2bf(float f) {
  unsigned int u = __float_as_uint(f);
  u += 0x7FFFu + ((u >> 16) & 1u);
  return (u16)(u >> 16);
}
__device__ __forceinline__ float bf2f(u16 h) {
  return __uint_as_float(((unsigned int)h) << 16);
}

// ---------------- K1: LayerNorm(pair) -> PNb (bf16) ----------------
__global__ __launch_bounds__(256) void k_ln(const float* __restrict__ x,
                                            const float* __restrict__ g,
                                            const float* __restrict__ b,
                                            u16* __restrict__ y) {
  int p = blockIdx.x * 4 + (threadIdx.x >> 6);
  int lane = threadIdx.x & 63;
  float2 xv = *(const float2*)(x + (size_t)p * 128 + lane * 2);
  float x0 = xv.x, x1 = xv.y;
  float s = x0 + x1, ss = x0 * x0 + x1 * x1;
#pragma unroll
  for (int off = 32; off; off >>= 1) {
    s += __shfl_xor(s, off);
    ss += __shfl_xor(ss, off);
  }
  float m = s * (1.0f / 128.0f);
  float v = ss * (1.0f / 128.0f) - m * m;
  float inv = rsqrtf(v + 1e-5f);
  float2 gv = *(const float2*)(g + lane * 2);
  float2 bv = *(const float2*)(b + lane * 2);
  float y0 = (x0 - m) * inv * gv.x + bv.x;
  float y1 = (x1 - m) * inv * gv.y + bv.y;
  unsigned int pk = (unsigned int)f2bf(y0) | ((unsigned int)f2bf(y1) << 16);
  *(unsigned int*)(y + (size_t)p * 128 + lane * 2) = pk;
}

// ---------------- K2: LayerNorm(bias) -> Bp (fp32) ----------------
__global__ __launch_bounds__(256) void k_lnbias_bproj(const float* __restrict__ x,
                                                      const float* __restrict__ g,
                                                      const float* __restrict__ b,
                                                      const float* __restrict__ Wb,
                                                      float* __restrict__ Bp) {
  const int t = threadIdx.x;
  const int row = t >> 3, h = t & 7;
  const int p = blockIdx.x * 32 + row;
  const int r = p >> 8, sc = p & 255;
  const float* rp = x + (size_t)p * 128 + h * 16;
  float4 xv[4];
#pragma unroll
  for (int i = 0; i < 4; ++i) xv[i] = ((const float4*)rp)[i];
  float s = 0.f, ss = 0.f;
#pragma unroll
  for (int i = 0; i < 4; ++i) {
    s += (xv[i].x + xv[i].y) + (xv[i].z + xv[i].w);
    ss += (xv[i].x * xv[i].x + xv[i].y * xv[i].y) + (xv[i].z * xv[i].z + xv[i].w * xv[i].w);
  }
#pragma unroll
  for (int off = 1; off <= 4; off <<= 1) {
    s += __shfl_xor(s, off);
    ss += __shfl_xor(ss, off);
  }
  float m = s * (1.0f / 128.0f);
  float var = ss * (1.0f / 128.0f) - m * m;
  float inv = rsqrtf(var + 1e-5f);
  float part[8];
#pragma unroll
  for (int hh = 0; hh < 8; ++hh) part[hh] = 0.f;
  const float4* g4 = (const float4*)(g + h * 16);
  const float4* b4 = (const float4*)(b + h * 16);
#pragma unroll
  for (int i4 = 0; i4 < 4; ++i4) {
    float4 gv = g4[i4], bv = b4[i4];
    float xs[4] = {xv[i4].x, xv[i4].y, xv[i4].z, xv[i4].w};
    float gs[4] = {gv.x, gv.y, gv.z, gv.w};
    float bs[4] = {bv.x, bv.y, bv.z, bv.w};
#pragma unroll
    for (int q = 0; q < 4; ++q) {
      int k = h * 16 + i4 * 4 + q;
      float xn = (xs[q] - m) * inv * gs[q] + bs[q];
      float4 w0 = *(const float4*)(Wb + k * 8);
      float4 w1 = *(const float4*)(Wb + k * 8 + 4);
      part[0] += xn * w0.x;
      part[1] += xn * w0.y;
      part[2] += xn * w0.z;
      part[3] += xn * w0.w;
      part[4] += xn * w1.x;
      part[5] += xn * w1.y;
      part[6] += xn * w1.z;
      part[7] += xn * w1.w;
    }
  }
#pragma unroll
  for (int off = 1; off <= 4; off <<= 1) {
#pragma unroll
    for (int hh = 0; hh < 8; ++hh) part[hh] += __shfl_xor(part[hh], off);
  }
  float val = (h == 0) ? part[0]
            : (h == 1) ? part[1]
            : (h == 2) ? part[2]
            : (h == 3) ? part[3]
            : (h == 4) ? part[4]
            : (h == 5) ? part[5]
            : (h == 6) ? part[6]
                       : part[7];
  Bp[(size_t)h * 65536 + (size_t)sc * 256 + r] = val;
}

// ---------------- K3: weight convert/transpose to bf16 ----------------
__global__ __launch_bounds__(256) void k_wcvt(const float* __restrict__ Wq,
                                              const float* __restrict__ Wk,
                                              const float* __restrict__ Wv,
                                              const float* __restrict__ Wg,
                                              const float* __restrict__ Wo,
                                              u16* __restrict__ Wtb,
                                              u16* __restrict__ Wotb) {
  int idx = blockIdx.x * 256 + threadIdx.x;
  if (idx < 131072) {
    int w = idx >> 15, r = idx & 32767;
    int n = r >> 7, k = r & 127;  // out [n][k]
    const float* W = (w == 0) ? Wq : (w == 1) ? Wk : (w == 2) ? Wv : Wg;
    Wtb[(size_t)w * 32768 + n * 128 + k] = f2bf(W[k * 256 + n]);
  } else {
    int r = idx - 131072;  // Wo [256 e][128 c] -> Wotb[c][e]
    int c = r >> 8, e = r & 255;
    Wotb[c * 256 + e] = f2bf(Wo[e * 128 + c]);
  }
}

// ---------------- K4 v3: Q/K/gate projections, tiled packed stores ----------
// grid (128 stripes, 4 col-quarters, 3 weights). No LDS, no barriers.
// D-frag rows (quad*4+reg) pack into one 8B store per (mt,nt) in the tiled
// layout X4[(p>>2)*1024 + n*4 + (p&3)].
__global__ __launch_bounds__(256) void k_proj_qkg(const u16* __restrict__ PNb,
                                                  const u16* __restrict__ Wtb,
                                                  const float* __restrict__ bg,
                                                  u16* __restrict__ Qr4,
                                                  u16* __restrict__ Kr4,
                                                  u16* __restrict__ G2) {
  const int t = threadIdx.x;
  const int wid = t >> 6, lane = t & 63;
  const int mrow = lane & 15, quad = lane >> 4;
  const int stripe = blockIdx.x;
  const int n0 = blockIdx.y * 64;
  const int wsel3 = blockIdx.z;  // 0:Q 1:K 2:G
  const int wsel = (wsel3 == 2) ? 3 : wsel3;
  const u16* Wt = Wtb + (size_t)wsel * 32768;
  u16* dst = (wsel3 == 0) ? Qr4 : (wsel3 == 1) ? Kr4 : G2;

  short8 bfr[4][4];
#pragma unroll
  for (int nt = 0; nt < 4; ++nt)
#pragma unroll
    for (int kk = 0; kk < 4; ++kk)
      bfr[nt][kk] = *(const short8*)(Wt + (size_t)(n0 + nt * 16 + mrow) * 128 + kk * 32 + quad * 8);

  float bgv[4];
#pragma unroll
  for (int nt = 0; nt < 4; ++nt) bgv[nt] = bg[n0 + nt * 16 + mrow];

  for (int it = 0; it < 4; ++it) {
    const int pw = stripe * 512 + it * 128 + wid * 32;
    short8 afr[2][4];
#pragma unroll
    for (int mt = 0; mt < 2; ++mt)
#pragma unroll
      for (int kk = 0; kk < 4; ++kk)
        afr[mt][kk] =
            *(const short8*)(PNb + (size_t)(pw + mt * 16 + mrow) * 128 + kk * 32 + quad * 8);
    float4v acc[2][4];
#pragma unroll
    for (int mt = 0; mt < 2; ++mt)
#pragma unroll
      for (int nt = 0; nt < 4; ++nt) acc[mt][nt] = (float4v){0.f, 0.f, 0.f, 0.f};
#pragma unroll
    for (int kk = 0; kk < 4; ++kk)
#pragma unroll
      for (int mt = 0; mt < 2; ++mt)
#pragma unroll
        for (int nt = 0; nt < 4; ++nt)
          acc[mt][nt] = __builtin_amdgcn_mfma_f32_16x16x32_bf16(afr[mt][kk], bfr[nt][kk],
                                                                acc[mt][nt], 0, 0, 0);
#pragma unroll
    for (int mt = 0; mt < 2; ++mt) {
      const int prow4 = ((pw + mt * 16) >> 2) + quad;  // p>>2 for this lane's 4 rows
#pragma unroll
      for (int nt = 0; nt < 4; ++nt) {
        const int n = n0 + nt * 16 + mrow;
        short4v pk;
#pragma unroll
        for (int reg = 0; reg < 4; ++reg) {
          float v = acc[mt][nt][reg];
          if (wsel3 == 0) v *= 0.17677669529663687f;
          else if (wsel3 == 1) v *= 0.0625f;
          else v = 1.f / (1.f + expf(-(v + bgv[nt])));
          pk[reg] = (short)f2bf(v);
        }
        *(short4v*)(dst + ((size_t)prow4 * 256 + n) * 4) = pk;
      }
    }
  }
}

// ---------------- K5: V projection (MFMA), tiled by fixed sc, 128 r-rows ----
__global__ __launch_bounds__(256) void k_projv(const u16* __restrict__ PNb,
                                               const u16* __restrict__ Wtb,
                                               u16* __restrict__ Vtb) {
  __shared__ u16 sb[128 * 136];
  const int t = threadIdx.x;
  const int wid = t >> 6, lane = t & 63;
  const int mrow = lane & 15, quad = lane >> 4;
  const int sc = blockIdx.x >> 1;
  const int r0 = (blockIdx.x & 1) * 128;
  short8 afr[2][4];
#pragma unroll
  for (int mt = 0; mt < 2; ++mt) {
    const int p = (r0 + wid * 32 + mt * 16 + mrow) * 256 + sc;
    const u16* ar = PNb + (size_t)p * 128 + quad * 8;
#pragma unroll
    for (int kk = 0; kk < 4; ++kk) afr[mt][kk] = *(const short8*)(ar + kk * 32);
  }
  const u16* Wt = Wtb + (size_t)2 * 32768;
  for (int half = 0; half < 2; ++half) {
#pragma unroll
    for (int nt8 = 0; nt8 < 8; ++nt8) {
      const int nt = half * 8 + nt8;
      float4v acc[2];
      acc[0] = (float4v){0.f, 0.f, 0.f, 0.f};
      acc[1] = (float4v){0.f, 0.f, 0.f, 0.f};
      const u16* br = Wt + (size_t)(nt * 16 + mrow) * 128 + quad * 8;
#pragma unroll
      for (int kk = 0; kk < 4; ++kk) {
        short8 bfr = *(const short8*)(br + kk * 32);
#pragma unroll
        for (int mt = 0; mt < 2; ++mt)
          acc[mt] = __builtin_amdgcn_mfma_f32_16x16x32_bf16(afr[mt][kk], bfr, acc[mt], 0, 0, 0);
      }
#pragma unroll
      for (int mt = 0; mt < 2; ++mt)
#pragma unroll
        for (int reg = 0; reg < 4; ++reg)
          sb[(wid * 32 + mt * 16 + quad * 4 + reg) * 136 + nt8 * 16 + mrow] =
              f2bf(acc[mt][reg]);
    }
    __syncthreads();
#pragma unroll
    for (int it = 0; it < 8; ++it) {
      int u = it * 256 + t;
      int c = u & 127, rg = u >> 7;
      short8 vv;
#pragma unroll
      for (int q = 0; q < 8; ++q) vv[q] = (short)sb[(rg * 8 + q) * 136 + c];
      int n = half * 128 + c;
      int h = n >> 5, d = n & 31;
      *(short8*)(Vtb + (size_t)h * 2097152 + (size_t)(sc * 32 + d) * 256 + r0 + rg * 8) = vv;
    }
    __syncthreads();
  }
}

// ---------------- K6 v2: logits (MFMA) from tiled Qr4/Kr4 ----------------
// grid (4 = 2 i-tiles x 2 j-tiles, 8 h, 16 kslabs of 16 sc). Contraction
// relabeled k = 4*d + (sc&3) per 4-sc group (Q and K use identical labels).
// Staging: 16B global chunks are contiguous in the tiled layout.
__global__ __launch_bounds__(256) void k_logits_mfma(const u16* __restrict__ Qr4,
                                                     const u16* __restrict__ Kr4,
                                                     float* __restrict__ Lg2) {
  __shared__ u16 Qs[128 * 72];
  __shared__ u16 Ks[128 * 72];
  const int t = threadIdx.x;
  const int wid = t >> 6, lane = t & 63;
  const int mrow = lane & 15, quad = lane >> 4;
  const int i0 = (blockIdx.x >> 1) * 128, j0 = (blockIdx.x & 1) * 128;
  const int h = blockIdx.y;
  const int z = blockIdx.z;  // 0..15
  const int wi = wid >> 1, wj = wid & 1;
  float4v acc[4][4];
#pragma unroll
  for (int a = 0; a < 4; ++a)
#pragma unroll
    for (int bq = 0; bq < 4; ++bq) acc[a][bq] = (float4v){0.f, 0.f, 0.f, 0.f};

  for (int g = 0; g < 4; ++g) {       // 4-sc groups in this slab
    const int sc4 = z * 4 + g;
    for (int sub = 0; sub < 2; ++sub) {  // k-halves of 64
      __syncthreads();
      // stage: 2 mats x 128 rows x 8 chunks(16B) = 2048 units, 8 iters
#pragma unroll
      for (int itq = 0; itq < 4; ++itq) {
        int u = itq * 256 + t;  // 0..1023: i=u>>3, c=u&7
        int i_loc = u >> 3, c16 = sub * 8 + (u & 7);
        size_t qoff = ((size_t)((i0 + i_loc) * 64 + sc4) * 256 + h * 32 + c16 * 2) * 4;
        *(short8*)&Qs[i_loc * 72 + (u & 7) * 8] = *(const short8*)(Qr4 + qoff);
        size_t koff = ((size_t)((j0 + i_loc) * 64 + sc4) * 256 + h * 32 + c16 * 2) * 4;
        *(short8*)&Ks[i_loc * 72 + (u & 7) * 8] = *(const short8*)(Kr4 + koff);
      }
      __syncthreads();
#pragma unroll
      for (int kk = 0; kk < 2; ++kk) {
        short8 afr[4], bfr[4];
#pragma unroll
        for (int mt = 0; mt < 4; ++mt)
          afr[mt] = *(const short8*)&Qs[(wi * 64 + mt * 16 + mrow) * 72 + kk * 32 + quad * 8];
#pragma unroll
        for (int nn = 0; nn < 4; ++nn)
          bfr[nn] = *(const short8*)&Ks[(wj * 64 + nn * 16 + mrow) * 72 + kk * 32 + quad * 8];
#pragma unroll
        for (int mt = 0; mt < 4; ++mt)
#pragma unroll
          for (int nn = 0; nn < 4; ++nn)
            acc[mt][nn] =
                __builtin_amdgcn_mfma_f32_16x16x32_bf16(afr[mt], bfr[nn], acc[mt][nn], 0, 0, 0);
      }
    }
  }
  float* slab = Lg2 + ((size_t)z * 8 + h) * 65536;
#pragma unroll
  for (int mt = 0; mt < 4; ++mt)
#pragma unroll
    for (int nn = 0; nn < 4; ++nn) {
      int j = j0 + wj * 64 + nn * 16 + mrow;
#pragma unroll
      for (int reg = 0; reg < 4; ++reg) {
        int i = i0 + wi * 64 + mt * 16 + quad * 4 + reg;
        slab[(size_t)i * 256 + j] = acc[mt][nn][reg];
      }
    }
}

// ---------------- K7: masked softmax over j (sum Bp + 16 slabs) -> Ab --------
__global__ __launch_bounds__(256) void k_softmax(const float* __restrict__ Bp,
                                                 const float* __restrict__ Lg2,
                                                 const int* __restrict__ mask,
                                                 u16* __restrict__ Ab) {
  const int i = blockIdx.x, h = blockIdx.y;
  const int j = threadIdx.x;
  __shared__ float red[4], red2[4];
  const size_t off = (size_t)h * 65536 + (size_t)i * 256 + j;
  float x = Bp[off];
#pragma unroll
  for (int z = 0; z < 16; ++z) x += Lg2[(size_t)z * 524288 + off];
  bool mi = (mask[i] == 0);
  if (mi || (mask[j] == 0)) x = -1e9f;
  float mx = x;
#pragma unroll
  for (int off2 = 32; off2; off2 >>= 1) mx = fmaxf(mx, __shfl_xor(mx, off2));
  int wave = j >> 6;
  if ((j & 63) == 0) red[wave] = mx;
  __syncthreads();
  mx = fmaxf(fmaxf(red[0], red[1]), fmaxf(red[2], red[3]));
  float e = expf(x - mx);
  float sm = e;
#pragma unroll
  for (int off2 = 32; off2; off2 >>= 1) sm += __shfl_xor(sm, off2);
  if ((j & 63) == 0) red2[wave] = sm;
  __syncthreads();
  sm = red2[0] + red2[1] + red2[2] + red2[3];
  Ab[off] = f2bf(e / sm);
}

// ---------------- K8: AV (MFMA) + gate (b64 tiled loads) -> GOb --------------
__global__ __launch_bounds__(256) void k_av_mfma(const u16* __restrict__ Ab,
                                                 const u16* __restrict__ Vtb,
                                                 const u16* __restrict__ G2,
                                                 u16* __restrict__ GOb) {
  __shared__ u16 As[64 * 264];
  const int t = threadIdx.x;
  const int wid = t >> 6, lane = t & 63;
  const int mrow = lane & 15, quad = lane >> 4;
  const int h = blockIdx.z;
  const int i0 = blockIdx.y * 64;
  const u16* ag = Ab + (size_t)h * 65536 + (size_t)i0 * 256;
#pragma unroll
  for (int u = 0; u < 8; ++u) {
    int id = u * 256 + t;
    int rr = id >> 5, c8 = (id & 31) * 8;
    *(short8*)&As[rr * 264 + c8] = *(const short8*)(ag + (size_t)rr * 256 + c8);
  }
  __syncthreads();
  const u16* vg = Vtb + (size_t)h * 2097152;
  for (int nt4 = 0; nt4 < 4; ++nt4) {
    const int nbase = blockIdx.x * 1024 + wid * 256 + nt4 * 64;
    float4v acc[4][4];
#pragma unroll
    for (int a = 0; a < 4; ++a)
#pragma unroll
      for (int bq = 0; bq < 4; ++bq) acc[a][bq] = (float4v){0.f, 0.f, 0.f, 0.f};
#pragma unroll
    for (int kk = 0; kk < 8; ++kk) {
      short8 afr[4], bfr[4];
#pragma unroll
      for (int mt = 0; mt < 4; ++mt)
        afr[mt] = *(const short8*)&As[(mt * 16 + mrow) * 264 + kk * 32 + quad * 8];
#pragma unroll
      for (int nn = 0; nn < 4; ++nn)
        bfr[nn] = *(const short8*)(vg + (size_t)(nbase + nn * 16 + mrow) * 256 + kk * 32 + quad * 8);
#pragma unroll
      for (int mt = 0; mt < 4; ++mt)
#pragma unroll
        for (int nn = 0; nn < 4; ++nn)
          acc[mt][nn] = __builtin_amdgcn_mfma_f32_16x16x32_bf16(afr[mt], bfr[nn], acc[mt][nn], 0, 0, 0);
    }
#pragma unroll
    for (int mt = 0; mt < 4; ++mt)
#pragma unroll
      for (int nn = 0; nn < 4; ++nn) {
        const int kslot = (nbase + nn * 16) >> 5;
        const int d = (nn & 1) * 16 + mrow;
        const int e = h * 32 + d;
        // gate: p = kslot*256 + i, lane's 4 regs are consecutive p -> b64 load
        const int p4 = kslot * 64 + ((i0 + mt * 16) >> 2) + quad;
        short4v g4 = *(const short4v*)(G2 + ((size_t)p4 * 256 + e) * 4);
#pragma unroll
        for (int reg = 0; reg < 4; ++reg) {
          int i = i0 + mt * 16 + quad * 4 + reg;
          size_t idx = ((size_t)i * 256 + kslot) * 256 + e;
          float gv = bf2f((u16)g4[reg]);
          GOb[idx] = f2bf(acc[mt][nn][reg] * gv);
        }
      }
  }
}

// ---------------- K9: output proj (MFMA) + bias + transpose + mask ----------------
__global__ __launch_bounds__(256) void k_out_mfma(const u16* __restrict__ GOb,
                                                  const u16* __restrict__ Wotb,
                                                  const float* __restrict__ bo,
                                                  const int* __restrict__ mask,
                                                  float* __restrict__ out) {
  const int wid = threadIdx.x >> 6, lane = threadIdx.x & 63;
  const int mrow = lane & 15, quad = lane >> 4;
  const int m0 = blockIdx.x * 128 + wid * 32;
  short8 afr[2][8];
#pragma unroll
  for (int mt = 0; mt < 2; ++mt) {
    const u16* ar = GOb + (size_t)(m0 + mt * 16 + mrow) * 256 + quad * 8;
#pragma unroll
    for (int kk = 0; kk < 8; ++kk) afr[mt][kk] = *(const short8*)(ar + kk * 32);
  }
  for (int nt = 0; nt < 8; ++nt) {
    float4v acc[2];
    acc[0] = (float4v){0.f, 0.f, 0.f, 0.f};
    acc[1] = (float4v){0.f, 0.f, 0.f, 0.f};
    const u16* br = Wotb + (size_t)(nt * 16 + mrow) * 256 + quad * 8;
#pragma unroll
    for (int kk = 0; kk < 8; ++kk) {
      short8 bfr = *(const short8*)(br + kk * 32);
#pragma unroll
      for (int mt = 0; mt < 2; ++mt)
        acc[mt] = __builtin_amdgcn_mfma_f32_16x16x32_bf16(afr[mt][kk], bfr, acc[mt], 0, 0, 0);
    }
    const int c = nt * 16 + mrow;
    float bov = bo[c];
#pragma unroll
    for (int mt = 0; mt < 2; ++mt) {
#pragma unroll
      for (int reg = 0; reg < 4; ++reg) {
        int m = m0 + mt * 16 + quad * 4 + reg;  // = i*256 + k
        int i = m >> 8, kq = m & 255;
        float v = acc[mt][reg] + bov;
        bool z = (mask[i] == 0) || (mask[kq] == 0);
        out[((size_t)kq * 256 + i) * 128 + c] = z ? 0.f : v;
      }
    }
  }
}

extern "C" void kernel_launch(void* const* d_in, const int* in_sizes, int n_in,
                              void* d_out, int out_size, void* d_ws, size_t ws_size,
                              hipStream_t stream) {
  const float* pair = (const float*)d_in[0];
  const float* bias = (const float*)d_in[1];
  const int* mask = (const int*)d_in[2];
  const float* g_pair = (const float*)d_in[3];
  const float* b_pair = (const float*)d_in[4];
  const float* g_bias = (const float*)d_in[5];
  const float* b_bias = (const float*)d_in[6];
  const float* Wq = (const float*)d_in[7];
  const float* Wk = (const float*)d_in[8];
  const float* Wv = (const float*)d_in[9];
  const float* Wb = (const float*)d_in[10];
  const float* Wg = (const float*)d_in[11];
  const float* bg = (const float*)d_in[12];
  const float* Wo = (const float*)d_in[13];
  const float* bo = (const float*)d_in[14];
  float* out = (float*)d_out;
  char* ws = (char*)d_ws;

  u16* PNb = (u16*)(ws + 0);
  u16* Qr4 = (u16*)(ws + 16777216);
  u16* Kr4 = (u16*)(ws + 50331648);
  u16* Vtb = (u16*)(ws + 83886080);
  u16* G2 = (u16*)(ws + 117440512);
  u16* GOb = (u16*)(ws + 150994944);
  float* Bp = (float*)(ws + 184549376);
  u16* Ab = (u16*)(ws + 186646528);
  u16* Wtb = (u16*)(ws + 187695104);
  u16* Wotb = (u16*)(ws + 187957248);
  float* Lg2 = (float*)(ws + 188022784);

  k_ln<<<16384, 256, 0, stream>>>(pair, g_pair, b_pair, PNb);
  k_wcvt<<<640, 256, 0, stream>>>(Wq, Wk, Wv, Wg, Wo, Wtb, Wotb);
  k_lnbias_bproj<<<2048, 256, 0, stream>>>(bias, g_bias, b_bias, Wb, Bp);
  k_proj_qkg<<<dim3(128, 4, 3), 256, 0, stream>>>(PNb, Wtb, bg, Qr4, Kr4, G2);
  k_projv<<<512, 256, 0, stream>>>(PNb, Wtb, Vtb);
  k_logits_mfma<<<dim3(4, 8, 16), 256, 0, stream>>>(Qr4, Kr4, Lg2);
  k_softmax<<<dim3(256, 8), 256, 0, stream>>>(Bp, Lg2, mask, Ab);
  k_av_mfma<<<dim3(8, 4, 8), 256, 0, stream>>>(Ab, Vtb, G2, GOb);
  k_out_mfma<<<512, 256, 0, stream>>>(GOb, Wotb, bo, mask, out);
}

// Round 9
// 331.746 us; speedup vs baseline: 2.9116x; 1.0194x over previous
//
#include <hip/hip_runtime.h>
#include <math.h>

// B=1, L=256, DP=128, DB=128, H=8, DH=32, H*DH=256
// bf16 MFMA 16x16x32. Q/K/G use a 4-row-tiled layout X4[(p>>2)][n][p&3];
// V projection stores D-fragments directly into Vtb (row axis j=r is the
// fast axis -> 8B packed stores, no LDS anywhere in the projections).
// NO atomics / cross-kernel RMW anywhere: bit-deterministic across replays.
//
// Fragment layouts (HW-verified):
//   A-frag: lane holds A[m=lane&15][k=(lane>>4)*8+j], j=0..7 (16B)
//   B-frag: lane holds B[k=(lane>>4)*8+j][n=lane&15]
//   D:      lane holds D[row=(lane>>4)*4+reg][col=lane&15]
//
// Workspace (byte offsets):
//   PNb  u16 [65536][128]     @ 0            16,777,216   LN(pair), row p=r*256+sc
//   Qr4  u16 tiled [16384][256][4] @ 16777216 33,554,432  (p>>2, n, p&3), p=(i,sc)
//   Kr4  u16 tiled             @ 50331648    33,554,432
//   Vtb  u16 [8][8192][256]   @ 83886080     33,554,432   [h][k*32+d][j]
//   G2   u16 tiled             @ 117440512   33,554,432   p = r*256+sc (= kslot*256+i)
//   GOb  u16 [65536][256]     @ 150994944    33,554,432   row = i*256+k
//   Bp   f32 [8][256][256]    @ 184549376     2,097,152
//   Ab   u16 [8][256][256]    @ 186646528     1,048,576
//   Wtb  u16 [4][256][128]    @ 187695104       262,144   W{q,k,v,g}^T [n][k]
//   Wotb u16 [128][256]       @ 187957248        65,536   Wo^T [c][e]
//   Lg2  f32 [16][8][256][256]@ 188022784    33,554,432   split-K logit slices
// total 221,577,216 B

typedef unsigned short u16;
typedef __attribute__((ext_vector_type(8))) short short8;
typedef __attribute__((ext_vector_type(4))) short short4v;
typedef __attribute__((ext_vector_type(4))) float float4v;

__device__ __forceinline__ u16 f2bf(float f) {
  unsigned int u = __float_as_uint(f);
  u += 0x7FFFu + ((u >> 16) & 1u);
  return (u16)(u >> 16);
}
__device__ __forceinline__ float bf2f(u16 h) {
  return __uint_as_float(((unsigned int)h) << 16);
}

// ---------------- K1: LayerNorm(pair) -> PNb (bf16) ----------------
__global__ __launch_bounds__(256) void k_ln(const float* __restrict__ x,
                                            const float* __restrict__ g,
                                            const float* __restrict__ b,
                                            u16* __restrict__ y) {
  int p = blockIdx.x * 4 + (threadIdx.x >> 6);
  int lane = threadIdx.x & 63;
  float2 xv = *(const float2*)(x + (size_t)p * 128 + lane * 2);
  float x0 = xv.x, x1 = xv.y;
  float s = x0 + x1, ss = x0 * x0 + x1 * x1;
#pragma unroll
  for (int off = 32; off; off >>= 1) {
    s += __shfl_xor(s, off);
    ss += __shfl_xor(ss, off);
  }
  float m = s * (1.0f / 128.0f);
  float v = ss * (1.0f / 128.0f) - m * m;
  float inv = rsqrtf(v + 1e-5f);
  float2 gv = *(const float2*)(g + lane * 2);
  float2 bv = *(const float2*)(b + lane * 2);
  float y0 = (x0 - m) * inv * gv.x + bv.x;
  float y1 = (x1 - m) * inv * gv.y + bv.y;
  unsigned int pk = (unsigned int)f2bf(y0) | ((unsigned int)f2bf(y1) << 16);
  *(unsigned int*)(y + (size_t)p * 128 + lane * 2) = pk;
}

// ---------------- K2: LayerNorm(bias) -> Bp (fp32) ----------------
__global__ __launch_bounds__(256) void k_lnbias_bproj(const float* __restrict__ x,
                                                      const float* __restrict__ g,
                                                      const float* __restrict__ b,
                                                      const float* __restrict__ Wb,
                                                      float* __restrict__ Bp) {
  const int t = threadIdx.x;
  const int row = t >> 3, h = t & 7;
  const int p = blockIdx.x * 32 + row;
  const int r = p >> 8, sc = p & 255;
  const float* rp = x + (size_t)p * 128 + h * 16;
  float4 xv[4];
#pragma unroll
  for (int i = 0; i < 4; ++i) xv[i] = ((const float4*)rp)[i];
  float s = 0.f, ss = 0.f;
#pragma unroll
  for (int i = 0; i < 4; ++i) {
    s += (xv[i].x + xv[i].y) + (xv[i].z + xv[i].w);
    ss += (xv[i].x * xv[i].x + xv[i].y * xv[i].y) + (xv[i].z * xv[i].z + xv[i].w * xv[i].w);
  }
#pragma unroll
  for (int off = 1; off <= 4; off <<= 1) {
    s += __shfl_xor(s, off);
    ss += __shfl_xor(ss, off);
  }
  float m = s * (1.0f / 128.0f);
  float var = ss * (1.0f / 128.0f) - m * m;
  float inv = rsqrtf(var + 1e-5f);
  float part[8];
#pragma unroll
  for (int hh = 0; hh < 8; ++hh) part[hh] = 0.f;
  const float4* g4 = (const float4*)(g + h * 16);
  const float4* b4 = (const float4*)(b + h * 16);
#pragma unroll
  for (int i4 = 0; i4 < 4; ++i4) {
    float4 gv = g4[i4], bv = b4[i4];
    float xs[4] = {xv[i4].x, xv[i4].y, xv[i4].z, xv[i4].w};
    float gs[4] = {gv.x, gv.y, gv.z, gv.w};
    float bs[4] = {bv.x, bv.y, bv.z, bv.w};
#pragma unroll
    for (int q = 0; q < 4; ++q) {
      int k = h * 16 + i4 * 4 + q;
      float xn = (xs[q] - m) * inv * gs[q] + bs[q];
      float4 w0 = *(const float4*)(Wb + k * 8);
      float4 w1 = *(const float4*)(Wb + k * 8 + 4);
      part[0] += xn * w0.x;
      part[1] += xn * w0.y;
      part[2] += xn * w0.z;
      part[3] += xn * w0.w;
      part[4] += xn * w1.x;
      part[5] += xn * w1.y;
      part[6] += xn * w1.z;
      part[7] += xn * w1.w;
    }
  }
#pragma unroll
  for (int off = 1; off <= 4; off <<= 1) {
#pragma unroll
    for (int hh = 0; hh < 8; ++hh) part[hh] += __shfl_xor(part[hh], off);
  }
  float val = (h == 0) ? part[0]
            : (h == 1) ? part[1]
            : (h == 2) ? part[2]
            : (h == 3) ? part[3]
            : (h == 4) ? part[4]
            : (h == 5) ? part[5]
            : (h == 6) ? part[6]
                       : part[7];
  Bp[(size_t)h * 65536 + (size_t)sc * 256 + r] = val;
}

// ---------------- K3: weight convert/transpose to bf16 ----------------
__global__ __launch_bounds__(256) void k_wcvt(const float* __restrict__ Wq,
                                              const float* __restrict__ Wk,
                                              const float* __restrict__ Wv,
                                              const float* __restrict__ Wg,
                                              const float* __restrict__ Wo,
                                              u16* __restrict__ Wtb,
                                              u16* __restrict__ Wotb) {
  int idx = blockIdx.x * 256 + threadIdx.x;
  if (idx < 131072) {
    int w = idx >> 15, r = idx & 32767;
    int n = r >> 7, k = r & 127;  // out [n][k]
    const float* W = (w == 0) ? Wq : (w == 1) ? Wk : (w == 2) ? Wv : Wg;
    Wtb[(size_t)w * 32768 + n * 128 + k] = f2bf(W[k * 256 + n]);
  } else {
    int r = idx - 131072;  // Wo [256 e][128 c] -> Wotb[c][e]
    int c = r >> 8, e = r & 255;
    Wotb[c * 256 + e] = f2bf(Wo[e * 128 + c]);
  }
}

// ---------------- K4 v3: Q/K/gate projections, tiled packed stores ----------
// grid (128 stripes, 4 col-quarters, 3 weights). No LDS, no barriers.
__global__ __launch_bounds__(256) void k_proj_qkg(const u16* __restrict__ PNb,
                                                  const u16* __restrict__ Wtb,
                                                  const float* __restrict__ bg,
                                                  u16* __restrict__ Qr4,
                                                  u16* __restrict__ Kr4,
                                                  u16* __restrict__ G2) {
  const int t = threadIdx.x;
  const int wid = t >> 6, lane = t & 63;
  const int mrow = lane & 15, quad = lane >> 4;
  const int stripe = blockIdx.x;
  const int n0 = blockIdx.y * 64;
  const int wsel3 = blockIdx.z;  // 0:Q 1:K 2:G
  const int wsel = (wsel3 == 2) ? 3 : wsel3;
  const u16* Wt = Wtb + (size_t)wsel * 32768;
  u16* dst = (wsel3 == 0) ? Qr4 : (wsel3 == 1) ? Kr4 : G2;

  short8 bfr[4][4];
#pragma unroll
  for (int nt = 0; nt < 4; ++nt)
#pragma unroll
    for (int kk = 0; kk < 4; ++kk)
      bfr[nt][kk] = *(const short8*)(Wt + (size_t)(n0 + nt * 16 + mrow) * 128 + kk * 32 + quad * 8);

  float bgv[4];
#pragma unroll
  for (int nt = 0; nt < 4; ++nt) bgv[nt] = bg[n0 + nt * 16 + mrow];

#pragma unroll 2
  for (int it = 0; it < 4; ++it) {
    const int pw = stripe * 512 + it * 128 + wid * 32;
    short8 afr[2][4];
#pragma unroll
    for (int mt = 0; mt < 2; ++mt)
#pragma unroll
      for (int kk = 0; kk < 4; ++kk)
        afr[mt][kk] =
            *(const short8*)(PNb + (size_t)(pw + mt * 16 + mrow) * 128 + kk * 32 + quad * 8);
    float4v acc[2][4];
#pragma unroll
    for (int mt = 0; mt < 2; ++mt)
#pragma unroll
      for (int nt = 0; nt < 4; ++nt) acc[mt][nt] = (float4v){0.f, 0.f, 0.f, 0.f};
#pragma unroll
    for (int kk = 0; kk < 4; ++kk)
#pragma unroll
      for (int mt = 0; mt < 2; ++mt)
#pragma unroll
        for (int nt = 0; nt < 4; ++nt)
          acc[mt][nt] = __builtin_amdgcn_mfma_f32_16x16x32_bf16(afr[mt][kk], bfr[nt][kk],
                                                                acc[mt][nt], 0, 0, 0);
#pragma unroll
    for (int mt = 0; mt < 2; ++mt) {
      const int prow4 = ((pw + mt * 16) >> 2) + quad;  // p>>2 for this lane's 4 rows
#pragma unroll
      for (int nt = 0; nt < 4; ++nt) {
        const int n = n0 + nt * 16 + mrow;
        short4v pk;
#pragma unroll
        for (int reg = 0; reg < 4; ++reg) {
          float v = acc[mt][nt][reg];
          if (wsel3 == 0) v *= 0.17677669529663687f;
          else if (wsel3 == 1) v *= 0.0625f;
          else v = 1.f / (1.f + expf(-(v + bgv[nt])));
          pk[reg] = (short)f2bf(v);
        }
        *(short4v*)(dst + ((size_t)prow4 * 256 + n) * 4) = pk;
      }
    }
  }
}

// ---------------- K5 v2: V projection, direct packed stores into Vtb --------
// grid (256 sc, 4 n-quarters). Output rows are r = j (Vtb fast axis), so the
// D-frag's 4 consecutive rows pack into one 8B store. No LDS, no barriers.
__global__ __launch_bounds__(256) void k_projv(const u16* __restrict__ PNb,
                                               const u16* __restrict__ Wtb,
                                               u16* __restrict__ Vtb) {
  const int t = threadIdx.x;
  const int wid = t >> 6, lane = t & 63;
  const int mrow = lane & 15, quad = lane >> 4;
  const int sc = blockIdx.x;
  const int n0 = blockIdx.y * 64;
  const u16* Wt = Wtb + (size_t)2 * 32768;

  short8 bfr[4][4];
#pragma unroll
  for (int nt = 0; nt < 4; ++nt)
#pragma unroll
    for (int kk = 0; kk < 4; ++kk)
      bfr[nt][kk] = *(const short8*)(Wt + (size_t)(n0 + nt * 16 + mrow) * 128 + kk * 32 + quad * 8);

#pragma unroll 2
  for (int it = 0; it < 2; ++it) {
    const int rbase = it * 128 + wid * 32;
    short8 afr[2][4];
#pragma unroll
    for (int mt = 0; mt < 2; ++mt)
#pragma unroll
      for (int kk = 0; kk < 4; ++kk)
        afr[mt][kk] = *(const short8*)(PNb + ((size_t)(rbase + mt * 16 + mrow) * 256 + sc) * 128 +
                                       kk * 32 + quad * 8);
    float4v acc[2][4];
#pragma unroll
    for (int mt = 0; mt < 2; ++mt)
#pragma unroll
      for (int nt = 0; nt < 4; ++nt) acc[mt][nt] = (float4v){0.f, 0.f, 0.f, 0.f};
#pragma unroll
    for (int kk = 0; kk < 4; ++kk)
#pragma unroll
      for (int mt = 0; mt < 2; ++mt)
#pragma unroll
        for (int nt = 0; nt < 4; ++nt)
          acc[mt][nt] = __builtin_amdgcn_mfma_f32_16x16x32_bf16(afr[mt][kk], bfr[nt][kk],
                                                                acc[mt][nt], 0, 0, 0);
#pragma unroll
    for (int mt = 0; mt < 2; ++mt) {
      const int j0 = rbase + mt * 16 + quad * 4;  // 4 consecutive j
#pragma unroll
      for (int nt = 0; nt < 4; ++nt) {
        const int n = n0 + nt * 16 + mrow;
        const int h = n >> 5, d = n & 31;
        short4v pk;
#pragma unroll
        for (int reg = 0; reg < 4; ++reg) pk[reg] = (short)f2bf(acc[mt][nt][reg]);
        *(short4v*)(Vtb + (size_t)h * 2097152 + (size_t)(sc * 32 + d) * 256 + j0) = pk;
      }
    }
  }
}

// ---------------- K6 v2: logits (MFMA) from tiled Qr4/Kr4 ----------------
__global__ __launch_bounds__(256) void k_logits_mfma(const u16* __restrict__ Qr4,
                                                     const u16* __restrict__ Kr4,
                                                     float* __restrict__ Lg2) {
  __shared__ u16 Qs[128 * 72];
  __shared__ u16 Ks[128 * 72];
  const int t = threadIdx.x;
  const int wid = t >> 6, lane = t & 63;
  const int mrow = lane & 15, quad = lane >> 4;
  const int i0 = (blockIdx.x >> 1) * 128, j0 = (blockIdx.x & 1) * 128;
  const int h = blockIdx.y;
  const int z = blockIdx.z;  // 0..15
  const int wi = wid >> 1, wj = wid & 1;
  float4v acc[4][4];
#pragma unroll
  for (int a = 0; a < 4; ++a)
#pragma unroll
    for (int bq = 0; bq < 4; ++bq) acc[a][bq] = (float4v){0.f, 0.f, 0.f, 0.f};

  for (int g = 0; g < 4; ++g) {
    const int sc4 = z * 4 + g;
    for (int sub = 0; sub < 2; ++sub) {
      __syncthreads();
#pragma unroll
      for (int itq = 0; itq < 4; ++itq) {
        int u = itq * 256 + t;
        int i_loc = u >> 3, c16 = sub * 8 + (u & 7);
        size_t qoff = ((size_t)((i0 + i_loc) * 64 + sc4) * 256 + h * 32 + c16 * 2) * 4;
        *(short8*)&Qs[i_loc * 72 + (u & 7) * 8] = *(const short8*)(Qr4 + qoff);
        size_t koff = ((size_t)((j0 + i_loc) * 64 + sc4) * 256 + h * 32 + c16 * 2) * 4;
        *(short8*)&Ks[i_loc * 72 + (u & 7) * 8] = *(const short8*)(Kr4 + koff);
      }
      __syncthreads();
#pragma unroll
      for (int kk = 0; kk < 2; ++kk) {
        short8 afr[4], bfr[4];
#pragma unroll
        for (int mt = 0; mt < 4; ++mt)
          afr[mt] = *(const short8*)&Qs[(wi * 64 + mt * 16 + mrow) * 72 + kk * 32 + quad * 8];
#pragma unroll
        for (int nn = 0; nn < 4; ++nn)
          bfr[nn] = *(const short8*)&Ks[(wj * 64 + nn * 16 + mrow) * 72 + kk * 32 + quad * 8];
#pragma unroll
        for (int mt = 0; mt < 4; ++mt)
#pragma unroll
          for (int nn = 0; nn < 4; ++nn)
            acc[mt][nn] =
                __builtin_amdgcn_mfma_f32_16x16x32_bf16(afr[mt], bfr[nn], acc[mt][nn], 0, 0, 0);
      }
    }
  }
  float* slab = Lg2 + ((size_t)z * 8 + h) * 65536;
#pragma unroll
  for (int mt = 0; mt < 4; ++mt)
#pragma unroll
    for (int nn = 0; nn < 4; ++nn) {
      int j = j0 + wj * 64 + nn * 16 + mrow;
#pragma unroll
      for (int reg = 0; reg < 4; ++reg) {
        int i = i0 + wi * 64 + mt * 16 + quad * 4 + reg;
        slab[(size_t)i * 256 + j] = acc[mt][nn][reg];
      }
    }
}

// ---------------- K7: masked softmax over j (sum Bp + 16 slabs) -> Ab --------
__global__ __launch_bounds__(256) void k_softmax(const float* __restrict__ Bp,
                                                 const float* __restrict__ Lg2,
                                                 const int* __restrict__ mask,
                                                 u16* __restrict__ Ab) {
  const int i = blockIdx.x, h = blockIdx.y;
  const int j = threadIdx.x;
  __shared__ float red[4], red2[4];
  const size_t off = (size_t)h * 65536 + (size_t)i * 256 + j;
  float x = Bp[off];
#pragma unroll
  for (int z = 0; z < 16; ++z) x += Lg2[(size_t)z * 524288 + off];
  bool mi = (mask[i] == 0);
  if (mi || (mask[j] == 0)) x = -1e9f;
  float mx = x;
#pragma unroll
  for (int off2 = 32; off2; off2 >>= 1) mx = fmaxf(mx, __shfl_xor(mx, off2));
  int wave = j >> 6;
  if ((j & 63) == 0) red[wave] = mx;
  __syncthreads();
  mx = fmaxf(fmaxf(red[0], red[1]), fmaxf(red[2], red[3]));
  float e = expf(x - mx);
  float sm = e;
#pragma unroll
  for (int off2 = 32; off2; off2 >>= 1) sm += __shfl_xor(sm, off2);
  if ((j & 63) == 0) red2[wave] = sm;
  __syncthreads();
  sm = red2[0] + red2[1] + red2[2] + red2[3];
  Ab[off] = f2bf(e / sm);
}

// ---------------- K8: AV (MFMA) + gate (b64 tiled loads) -> GOb --------------
__global__ __launch_bounds__(256) void k_av_mfma(const u16* __restrict__ Ab,
                                                 const u16* __restrict__ Vtb,
                                                 const u16* __restrict__ G2,
                                                 u16* __restrict__ GOb) {
  __shared__ u16 As[64 * 264];
  const int t = threadIdx.x;
  const int wid = t >> 6, lane = t & 63;
  const int mrow = lane & 15, quad = lane >> 4;
  const int h = blockIdx.z;
  const int i0 = blockIdx.y * 64;
  const u16* ag = Ab + (size_t)h * 65536 + (size_t)i0 * 256;
#pragma unroll
  for (int u = 0; u < 8; ++u) {
    int id = u * 256 + t;
    int rr = id >> 5, c8 = (id & 31) * 8;
    *(short8*)&As[rr * 264 + c8] = *(const short8*)(ag + (size_t)rr * 256 + c8);
  }
  __syncthreads();
  const u16* vg = Vtb + (size_t)h * 2097152;
  for (int nt4 = 0; nt4 < 4; ++nt4) {
    const int nbase = blockIdx.x * 1024 + wid * 256 + nt4 * 64;
    float4v acc[4][4];
#pragma unroll
    for (int a = 0; a < 4; ++a)
#pragma unroll
      for (int bq = 0; bq < 4; ++bq) acc[a][bq] = (float4v){0.f, 0.f, 0.f, 0.f};
#pragma unroll
    for (int kk = 0; kk < 8; ++kk) {
      short8 afr[4], bfr[4];
#pragma unroll
      for (int mt = 0; mt < 4; ++mt)
        afr[mt] = *(const short8*)&As[(mt * 16 + mrow) * 264 + kk * 32 + quad * 8];
#pragma unroll
      for (int nn = 0; nn < 4; ++nn)
        bfr[nn] = *(const short8*)(vg + (size_t)(nbase + nn * 16 + mrow) * 256 + kk * 32 + quad * 8);
#pragma unroll
      for (int mt = 0; mt < 4; ++mt)
#pragma unroll
        for (int nn = 0; nn < 4; ++nn)
          acc[mt][nn] = __builtin_amdgcn_mfma_f32_16x16x32_bf16(afr[mt], bfr[nn], acc[mt][nn], 0, 0, 0);
    }
#pragma unroll
    for (int mt = 0; mt < 4; ++mt)
#pragma unroll
      for (int nn = 0; nn < 4; ++nn) {
        const int kslot = (nbase + nn * 16) >> 5;
        const int d = (nn & 1) * 16 + mrow;
        const int e = h * 32 + d;
        const int p4 = kslot * 64 + ((i0 + mt * 16) >> 2) + quad;
        short4v g4 = *(const short4v*)(G2 + ((size_t)p4 * 256 + e) * 4);
#pragma unroll
        for (int reg = 0; reg < 4; ++reg) {
          int i = i0 + mt * 16 + quad * 4 + reg;
          size_t idx = ((size_t)i * 256 + kslot) * 256 + e;
          float gv = bf2f((u16)g4[reg]);
          GOb[idx] = f2bf(acc[mt][nn][reg] * gv);
        }
      }
  }
}

// ---------------- K9: output proj (MFMA) + bias + transpose + mask ----------------
__global__ __launch_bounds__(256) void k_out_mfma(const u16* __restrict__ GOb,
                                                  const u16* __restrict__ Wotb,
                                                  const float* __restrict__ bo,
                                                  const int* __restrict__ mask,
                                                  float* __restrict__ out) {
  const int wid = threadIdx.x >> 6, lane = threadIdx.x & 63;
  const int mrow = lane & 15, quad = lane >> 4;
  const int m0 = blockIdx.x * 128 + wid * 32;
  short8 afr[2][8];
#pragma unroll
  for (int mt = 0; mt < 2; ++mt) {
    const u16* ar = GOb + (size_t)(m0 + mt * 16 + mrow) * 256 + quad * 8;
#pragma unroll
    for (int kk = 0; kk < 8; ++kk) afr[mt][kk] = *(const short8*)(ar + kk * 32);
  }
  for (int nt = 0; nt < 8; ++nt) {
    float4v acc[2];
    acc[0] = (float4v){0.f, 0.f, 0.f, 0.f};
    acc[1] = (float4v){0.f, 0.f, 0.f, 0.f};
    const u16* br = Wotb + (size_t)(nt * 16 + mrow) * 256 + quad * 8;
#pragma unroll
    for (int kk = 0; kk < 8; ++kk) {
      short8 bfr = *(const short8*)(br + kk * 32);
#pragma unroll
      for (int mt = 0; mt < 2; ++mt)
        acc[mt] = __builtin_amdgcn_mfma_f32_16x16x32_bf16(afr[mt][kk], bfr, acc[mt], 0, 0, 0);
    }
    const int c = nt * 16 + mrow;
    float bov = bo[c];
#pragma unroll
    for (int mt = 0; mt < 2; ++mt) {
#pragma unroll
      for (int reg = 0; reg < 4; ++reg) {
        int m = m0 + mt * 16 + quad * 4 + reg;  // = i*256 + k
        int i = m >> 8, kq = m & 255;
        float v = acc[mt][reg] + bov;
        bool z = (mask[i] == 0) || (mask[kq] == 0);
        out[((size_t)kq * 256 + i) * 128 + c] = z ? 0.f : v;
      }
    }
  }
}

extern "C" void kernel_launch(void* const* d_in, const int* in_sizes, int n_in,
                              void* d_out, int out_size, void* d_ws, size_t ws_size,
                              hipStream_t stream) {
  const float* pair = (const float*)d_in[0];
  const float* bias = (const float*)d_in[1];
  const int* mask = (const int*)d_in[2];
  const float* g_pair = (const float*)d_in[3];
  const float* b_pair = (const float*)d_in[4];
  const float* g_bias = (const float*)d_in[5];
  const float* b_bias = (const float*)d_in[6];
  const float* Wq = (const float*)d_in[7];
  const float* Wk = (const float*)d_in[8];
  const float* Wv = (const float*)d_in[9];
  const float* Wb = (const float*)d_in[10];
  const float* Wg = (const float*)d_in[11];
  const float* bg = (const float*)d_in[12];
  const float* Wo = (const float*)d_in[13];
  const float* bo = (const float*)d_in[14];
  float* out = (float*)d_out;
  char* ws = (char*)d_ws;

  u16* PNb = (u16*)(ws + 0);
  u16* Qr4 = (u16*)(ws + 16777216);
  u16* Kr4 = (u16*)(ws + 50331648);
  u16* Vtb = (u16*)(ws + 83886080);
  u16* G2 = (u16*)(ws + 117440512);
  u16* GOb = (u16*)(ws + 150994944);
  float* Bp = (float*)(ws + 184549376);
  u16* Ab = (u16*)(ws + 186646528);
  u16* Wtb = (u16*)(ws + 187695104);
  u16* Wotb = (u16*)(ws + 187957248);
  float* Lg2 = (float*)(ws + 188022784);

  k_ln<<<16384, 256, 0, stream>>>(pair, g_pair, b_pair, PNb);
  k_wcvt<<<640, 256, 0, stream>>>(Wq, Wk, Wv, Wg, Wo, Wtb, Wotb);
  k_lnbias_bproj<<<2048, 256, 0, stream>>>(bias, g_bias, b_bias, Wb, Bp);
  k_proj_qkg<<<dim3(128, 4, 3), 256, 0, stream>>>(PNb, Wtb, bg, Qr4, Kr4, G2);
  k_projv<<<dim3(256, 4), 256, 0, stream>>>(PNb, Wtb, Vtb);
  k_logits_mfma<<<dim3(4, 8, 16), 256, 0, stream>>>(Qr4, Kr4, Lg2);
  k_softmax<<<dim3(256, 8), 256, 0, stream>>>(Bp, Lg2, mask, Ab);
  k_av_mfma<<<dim3(8, 4, 8), 256, 0, stream>>>(Ab, Vtb, G2, GOb);
  k_out_mfma<<<512, 256, 0, stream>>>(GOb, Wotb, bo, mask, out);
}